// Round 3
// baseline (482.977 us; speedup 1.0000x reference)
//
#include <hip/hip_runtime.h>
#include <math.h>

// Problem constants
constexpr int kB   = 4;
constexpr int kL   = 1024;
constexpr int kDM  = 768;
constexpr int kDI  = 1536;   // 2*kDM
constexpr int kDS  = 16;     // D_STATE
constexpr int kDTR = 48;     // DT_RANK
constexpr int kNX  = 80;     // DTR + 2*DS
constexpr int kM   = kB * kL; // 4096
constexpr int kLTXT = 128;

typedef __attribute__((ext_vector_type(8))) short bf16x8;
typedef __attribute__((ext_vector_type(4))) float f32x4;

__device__ inline unsigned short f2bf(float f) {
    unsigned u = __float_as_uint(f);
    u = (u + 0x7FFFu + ((u >> 16) & 1u)) >> 16;   // RNE
    return (unsigned short)u;
}

__device__ __forceinline__ void gl2lds16(const unsigned short* g, unsigned short* l) {
    __builtin_amdgcn_global_load_lds(
        (const __attribute__((address_space(1))) unsigned int*)g,
        (__attribute__((address_space(3))) unsigned int*)l, 16, 0, 0);
}

// ---------------------------------------------------------------------------
// txt[b][j] = b_txt[j] + sum_k text_tokens[b,0,k] * W_txt[j,k]
__global__ __launch_bounds__(256) void txt_kernel(
    const float* __restrict__ text, const float* __restrict__ Wt,
    const float* __restrict__ bt, float* __restrict__ txt)
{
    int gw = blockIdx.x * 4 + (threadIdx.x >> 6);
    int lane = threadIdx.x & 63;
    int b = gw / kDM;
    int j = gw - b * kDM;
    const float* trow = text + (size_t)b * kLTXT * kDM;
    const float* wrow = Wt + (size_t)j * kDM;
    float acc = 0.f;
    for (int k = lane; k < kDM; k += 64) acc = fmaf(trow[k], wrow[k], acc);
    #pragma unroll
    for (int o = 32; o; o >>= 1) acc += __shfl_xor(acc, o, 64);
    if (lane == 0) txt[gw] = acc + bt[j];
}

// ---------------------------------------------------------------------------
// tokens_bf16[m][k] = bf16(image[m][k] + txt[m/1024][k])
__global__ __launch_bounds__(256) void tokens_bf16_kernel(
    const float* __restrict__ img, const float* __restrict__ txt,
    unsigned short* __restrict__ tok)
{
    int i = blockIdx.x * 256 + threadIdx.x;        // over kM*kDM/4
    float4 a = ((const float4*)img)[i];
    int m = i / (kDM / 4);
    int k4 = i - m * (kDM / 4);
    float4 tv = ((const float4*)(txt + (size_t)(m >> 10) * kDM))[k4];
    ushort4 o;
    o.x = f2bf(a.x + tv.x); o.y = f2bf(a.y + tv.y);
    o.z = f2bf(a.z + tv.z); o.w = f2bf(a.w + tv.w);
    ((ushort4*)tok)[i] = o;
}

// ---------------------------------------------------------------------------
// cast in_proj_w (f32, [3072][768]) -> bf16
__global__ __launch_bounds__(256) void castw_kernel(
    const float* __restrict__ w, unsigned short* __restrict__ o, int n4)
{
    int i = blockIdx.x * 256 + threadIdx.x;
    if (i >= n4) return;
    float4 a = ((const float4*)w)[i];
    ushort4 v;
    v.x = f2bf(a.x); v.y = f2bf(a.y); v.z = f2bf(a.z); v.w = f2bf(a.w);
    ((ushort4*)o)[i] = v;
}

// ---------------------------------------------------------------------------
// bf16 MFMA GEMM for in_proj (m97 structure: global_load_lds width-16,
// double-buffered LDS, one barrier per K-step).
// M=4096, N=3072, K=768. BM=BN=128, BK=32, 256 threads (4 waves, 2x2).
// n<1536 -> xout; n>=1536 -> gout = silu(v)
__global__ __launch_bounds__(256) void mfma_inproj_kernel(
    const unsigned short* __restrict__ A, const unsigned short* __restrict__ W,
    float* __restrict__ xout, float* __restrict__ gout)
{
    __shared__ unsigned short Asm[2][128][32];
    __shared__ unsigned short Wsm[2][128][32];
    const int t = threadIdx.x;
    const int lane = t & 63;
    const int wv = t >> 6;             // wave 0..3
    const int wr = wv >> 1, wc = wv & 1;
    const int m0 = blockIdx.x * 128;
    const int n0 = blockIdx.y * 128;

    // staging: wave wv covers rows [wv*32, wv*32+32) in two 16-row segments.
    // lane l: row = seg*16 + (l>>2), 16B chunk (l&3) within the 64B row.
    const int srow = lane >> 2;          // 0..15
    const int scol = (lane & 3) * 8;     // bf16 elem 0,8,16,24
    const unsigned short* agp  = A + (size_t)(m0 + wv * 32 + srow) * kDM + scol;
    const unsigned short* agp2 = agp + 16 * kDM;
    const unsigned short* wgp  = W + (size_t)(n0 + wv * 32 + srow) * kDM + scol;
    const unsigned short* wgp2 = wgp + 16 * kDM;

    auto stage = [&](int buf, int k0) {
        gl2lds16(agp  + k0, &Asm[buf][wv * 32][0]);
        gl2lds16(agp2 + k0, &Asm[buf][wv * 32 + 16][0]);
        gl2lds16(wgp  + k0, &Wsm[buf][wv * 32][0]);
        gl2lds16(wgp2 + k0, &Wsm[buf][wv * 32 + 16][0]);
    };

    f32x4 acc[4][4] = {};
    const int fr = lane & 15;
    const int fk = (lane >> 4) * 8;

    stage(0, 0);
    __syncthreads();

    int buf = 0;
    for (int k0 = 0; k0 < kDM; k0 += 32) {
        if (k0 + 32 < kDM) stage(buf ^ 1, k0 + 32);
        bf16x8 af[4], wf[4];
        #pragma unroll
        for (int i = 0; i < 4; ++i)
            af[i] = *(const bf16x8*)&Asm[buf][wr * 64 + i * 16 + fr][fk];
        #pragma unroll
        for (int j = 0; j < 4; ++j)
            wf[j] = *(const bf16x8*)&Wsm[buf][wc * 64 + j * 16 + fr][fk];
        #pragma unroll
        for (int i = 0; i < 4; ++i)
            #pragma unroll
            for (int j = 0; j < 4; ++j)
                acc[i][j] = __builtin_amdgcn_mfma_f32_16x16x32_bf16(af[i], wf[j], acc[i][j], 0, 0, 0);
        __syncthreads();   // drains vmcnt (stage) + lgkmcnt; one barrier per K-step
        buf ^= 1;
    }

    // epilogue: row = (lane>>4)*4 + q, col = lane&15  (per 16x16 fragment)
    const int erow = (lane >> 4) * 4;
    const int ecol = lane & 15;
    #pragma unroll
    for (int i = 0; i < 4; ++i) {
        #pragma unroll
        for (int j = 0; j < 4; ++j) {
            const int gn = n0 + wc * 64 + j * 16 + ecol;
            #pragma unroll
            for (int q = 0; q < 4; ++q) {
                const int gm = m0 + wr * 64 + i * 16 + erow + q;
                float v = acc[i][j][q];
                if (gn < kDI) {
                    xout[(size_t)gm * kDI + gn] = v;
                } else {
                    gout[(size_t)gm * kDI + (gn - kDI)] = v / (1.f + __expf(-v));
                }
            }
        }
    }
}

// ---------------------------------------------------------------------------
// x_proj split-K: part[ks][m][n] = sum_{k in seg ks} x[m][k] * W[n][k]
// M=4096, N=80, K=1536 split into 8 segs of 192. Grid (64, 8).
constexpr int kKS   = 8;
constexpr int kKSEG = kDI / kKS;   // 192

__global__ __launch_bounds__(256) void xproj_splitk_kernel(
    const float* __restrict__ A, const float* __restrict__ W,
    float* __restrict__ part)
{
    __shared__ float As[16][68];
    __shared__ float Ws[16][84];
    const int t = threadIdx.x;
    const int m0 = blockIdx.x * 64;
    const int kbase = blockIdx.y * kKSEG;
    const int lrow = t >> 2, lk4 = (t & 3) << 2;
    const int ci = (t & 15) << 2;      // 4 rows
    const int cj = (t >> 4) * 5;       // 5 cols (16*5 = 80)
    float acc[4][5] = {};
    const float* aptr = A + (size_t)(m0 + lrow) * kDI + kbase + lk4;

    for (int k0 = 0; k0 < kKSEG; k0 += 16) {
        float4 av = *(const float4*)(aptr + k0);
        if (k0) __syncthreads();
        As[lk4+0][lrow] = av.x; As[lk4+1][lrow] = av.y;
        As[lk4+2][lrow] = av.z; As[lk4+3][lrow] = av.w;
        #pragma unroll
        for (int i = 0; i < 5; ++i) {           // 1280 W elems = 5/thread
            int idx = t + 256 * i;
            int n = idx % 80;
            int k = idx / 80;
            Ws[k][n] = W[(size_t)n * kDI + kbase + k0 + k];
        }
        __syncthreads();
        #pragma unroll
        for (int k = 0; k < 16; ++k) {
            const float4 a4 = *(const float4*)&As[k][ci];
            const float aa[4] = {a4.x, a4.y, a4.z, a4.w};
            float ww[5];
            #pragma unroll
            for (int j = 0; j < 5; ++j) ww[j] = Ws[k][cj + j];
            #pragma unroll
            for (int i = 0; i < 4; ++i)
                #pragma unroll
                for (int j = 0; j < 5; ++j)
                    acc[i][j] = fmaf(aa[i], ww[j], acc[i][j]);
        }
    }

    float* pbase = part + ((size_t)blockIdx.y * kM) * kNX;
    #pragma unroll
    for (int i = 0; i < 4; ++i)
        #pragma unroll
        for (int j = 0; j < 5; ++j)
            pbase[(size_t)(m0 + ci + i) * kNX + cj + j] = acc[i][j];
}

__global__ __launch_bounds__(256) void xproj_reduce_kernel(
    const float* __restrict__ part, float* __restrict__ xdbl)
{
    int i = blockIdx.x * 256 + threadIdx.x;    // over kM*kNX = 327680
    float s = 0.f;
    #pragma unroll
    for (int k = 0; k < kKS; ++k) s += part[(size_t)k * kM * kNX + i];
    xdbl[i] = s;
}

// ---------------------------------------------------------------------------
// dt_proj: dt[m][n] = softplus(sum_k x_dbl[m][k] * Wd[n][k] + b[n]), K=48.
// Block = 16 m-rows x 256 n-cols, thread-per-column, W tile in LDS (pad 49).
__global__ __launch_bounds__(256) void dtproj_kernel(
    const float* __restrict__ xdbl, const float* __restrict__ Wd,
    const float* __restrict__ bias, float* __restrict__ dt)
{
    __shared__ float As[16][49];
    __shared__ float Ws[256][49];
    const int t = threadIdx.x;
    const int m0 = blockIdx.x * 16;
    const int n0 = blockIdx.y * 256;
    if (t < 192) {                              // A tile: 16 x 48
        int m = t / 12, c4 = (t % 12) * 4;
        *(float4*)&As[m][c4] = *(const float4*)&xdbl[(size_t)(m0 + m) * kNX + c4];
    }
    #pragma unroll
    for (int i = 0; i < 12; ++i) {              // W tile: 256 x 48
        int idx = t + 256 * i;
        int r = idx / 12, c4 = (idx % 12) * 4;
        *(float4*)&Ws[r][c4] = *(const float4*)&Wd[(size_t)(n0 + r) * kDTR + c4];
    }
    __syncthreads();
    const float bn = bias[n0 + t];
    float acc[16] = {};
    #pragma unroll
    for (int k = 0; k < kDTR; ++k) {
        const float wv = Ws[t][k];
        #pragma unroll
        for (int m = 0; m < 16; ++m)
            acc[m] = fmaf(As[m][k], wv, acc[m]);
    }
    #pragma unroll
    for (int m = 0; m < 16; ++m) {
        float v = acc[m] + bn;
        v = (v > 20.f) ? v : log1pf(__expf(v));
        dt[(size_t)(m0 + m) * kDI + n0 + t] = v;
    }
}

// ---------------------------------------------------------------------------
// causal depthwise conv (k=4) + SiLU
__global__ __launch_bounds__(256) void conv_silu_kernel(
    const float* __restrict__ xraw, const float* __restrict__ cw,
    const float* __restrict__ cb, float* __restrict__ xout)
{
    int idx = blockIdx.x * 256 + threadIdx.x;   // over kM*kDI
    int d = idx % kDI;
    int ml = idx / kDI;
    int l = ml & (kL - 1);
    float acc = cb[d];
    const float* base = xraw + (size_t)ml * kDI + d - 3 * (size_t)kDI;
    const float* w = cw + d * 4;
    #pragma unroll
    for (int j = 0; j < 4; ++j) {
        if (l - 3 + j >= 0) acc = fmaf(base[(size_t)j * kDI], w[j], acc);
    }
    xout[idx] = acc / (1.f + __expf(-acc));
}

// ---------------------------------------------------------------------------
// Selective scan. Block = 256 threads = 16 channels x 16 states, one b.
// LDS double-buffered 64-step chunks; no per-step shuffles.
constexpr int kT  = 64;          // steps per chunk
constexpr int kNC = kL / kT;     // 16 chunks

__global__ __launch_bounds__(256) void scan2_kernel(
    const float* __restrict__ dt, const float* __restrict__ x,
    const float* __restrict__ g, const float* __restrict__ xdbl,
    const float* __restrict__ A_log, const float* __restrict__ Dvec,
    float* __restrict__ ysum)
{
    __shared__ float dtS[2][kT][16];
    __shared__ float uS [2][kT][16];
    __shared__ float gS [2][kT][16];
    __shared__ float BS [2][kT][16];
    __shared__ float CS [2][kT][16];
    const int t = threadIdx.x;
    const int b  = blockIdx.x / 96;            // 96 blocks per batch
    const int d0 = (blockIdx.x % 96) * 16;

    const int sl = t >> 2, sc = (t & 3) << 2;
    const float* dt_base = dt + ((size_t)b << 10) * kDI + d0;
    const float* x_base  = x  + ((size_t)b << 10) * kDI + d0;
    const float* g_base  = g  + ((size_t)b << 10) * kDI + d0;
    const float* bc_base = xdbl + ((size_t)b << 10) * kNX + kDTR;

    const int s = t & 15;     // state
    const int c = t >> 4;     // channel in block
    const int d = d0 + c;
    const float Aval = -__expf(A_log[d * kDS + s]);

    float4 r_dt, r_u, r_g, r_B, r_C;
    auto load_chunk = [&](int l0) {
        r_dt = *(const float4*)(dt_base + (size_t)(l0 + sl) * kDI + sc);
        r_u  = *(const float4*)(x_base  + (size_t)(l0 + sl) * kDI + sc);
        r_g  = *(const float4*)(g_base  + (size_t)(l0 + sl) * kDI + sc);
        r_B  = *(const float4*)(bc_base + (size_t)(l0 + sl) * kNX + sc);
        r_C  = *(const float4*)(bc_base + (size_t)(l0 + sl) * kNX + 16 + sc);
    };
    auto store_chunk = [&](int bf) {
        *(float4*)&dtS[bf][sl][sc] = r_dt;
        *(float4*)&uS [bf][sl][sc] = r_u;
        *(float4*)&gS [bf][sl][sc] = r_g;
        *(float4*)&BS [bf][sl][sc] = r_B;
        *(float4*)&CS [bf][sl][sc] = r_C;
    };

    load_chunk(0);
    store_chunk(0);
    __syncthreads();

    float h = 0.f, acc = 0.f, ug = 0.f;
    for (int ck = 0; ck < kNC; ++ck) {
        const int bu = ck & 1;
        if (ck + 1 < kNC) load_chunk((ck + 1) * kT);
        #pragma unroll 4
        for (int i = 0; i < kT; ++i) {
            const float dtv = dtS[bu][i][c];
            const float uv  = uS [bu][i][c];
            const float gv  = gS [bu][i][c];
            const float Bv  = BS [bu][i][s];
            const float Cv  = CS [bu][i][s];
            const float dA  = __expf(dtv * Aval);
            h   = fmaf(dA, h, dtv * uv * Bv);
            acc = fmaf(h * Cv, gv, acc);
            ug  = fmaf(uv, gv, ug);
        }
        if (ck + 1 < kNC) {
            __syncthreads();
            store_chunk(bu ^ 1);
            __syncthreads();
        }
    }

    #pragma unroll
    for (int o = 1; o < 16; o <<= 1) acc += __shfl_xor(acc, o, 64);
    if (s == 0) ysum[(size_t)b * kDI + d] = acc + Dvec[d] * ug;
}

// ---------------------------------------------------------------------------
// out[b][j] = (1/L) * sum_d ysum[b][d] * Wout[j][d]
__global__ __launch_bounds__(256) void final_kernel(
    const float* __restrict__ ysum, const float* __restrict__ Wout,
    float* __restrict__ out)
{
    int gw = blockIdx.x * 4 + (threadIdx.x >> 6);
    int lane = threadIdx.x & 63;
    int b = gw / kDM;
    int j = gw - b * kDM;
    const float* yrow = ysum + (size_t)b * kDI;
    const float* wrow = Wout + (size_t)j * kDI;
    float acc = 0.f;
    for (int k = lane; k < kDI; k += 64) acc = fmaf(yrow[k], wrow[k], acc);
    #pragma unroll
    for (int o = 32; o; o >>= 1) acc += __shfl_xor(acc, o, 64);
    if (lane == 0) out[gw] = acc * (1.f / (float)kL);
}

// ---------------------------------------------------------------------------
extern "C" void kernel_launch(void* const* d_in, const int* in_sizes, int n_in,
                              void* d_out, int out_size, void* d_ws, size_t ws_size,
                              hipStream_t stream)
{
    const float* image_tokens = (const float*)d_in[0];
    const float* text_tokens  = (const float*)d_in[1];
    const float* W_txt        = (const float*)d_in[2];
    const float* b_txt        = (const float*)d_in[3];
    const float* in_proj_w    = (const float*)d_in[4];
    const float* conv_w       = (const float*)d_in[5];
    const float* conv_b       = (const float*)d_in[6];
    const float* x_proj_w     = (const float*)d_in[7];
    const float* dt_proj_w    = (const float*)d_in[8];
    const float* dt_proj_b    = (const float*)d_in[9];
    const float* A_log        = (const float*)d_in[10];
    const float* Dvec         = (const float*)d_in[11];
    const float* out_proj_w   = (const float*)d_in[12];
    float* out = (float*)d_out;

    // workspace layout (bytes, all 256B-aligned)
    char* p = (char*)d_ws;
    float* txt = (float*)p;                       p += 12288;
    unsigned short* tokb = (unsigned short*)p;    p += (size_t)kM * kDM * 2;       // 6.3 MB
    unsigned short* wb   = (unsigned short*)p;    p += (size_t)2 * kDI * kDM * 2;  // 4.7 MB
    float* xraw = (float*)p;                      p += (size_t)kM * kDI * 4;       // 25.2 MB (reused as dt)
    float* gbuf = (float*)p;                      p += (size_t)kM * kDI * 4;       // 25.2 MB
    float* xbuf = (float*)p;                      p += (size_t)kM * kDI * 4;       // 25.2 MB
    float* xdbl = (float*)p;                      p += (size_t)kM * kNX * 4;       // 1.3 MB
    float* ysum = (float*)p;                      p += (size_t)kB * kDI * 4;
    float* dt = xraw;                 // xraw dead after conv
    float* part = (float*)tokb;       // 10.5 MB; tokb+wb (11 MB) dead after in_proj

    // 1) txt projection
    txt_kernel<<<dim3(kB * kDM / 4), dim3(256), 0, stream>>>(text_tokens, W_txt, b_txt, txt);

    // 2) tokens = bf16(image + txt)
    tokens_bf16_kernel<<<dim3(kM * kDM / 4 / 256), dim3(256), 0, stream>>>(image_tokens, txt, tokb);

    // 3) cast in_proj_w to bf16
    castw_kernel<<<dim3((2 * kDI * kDM / 4 + 255) / 256), dim3(256), 0, stream>>>(
        in_proj_w, wb, 2 * kDI * kDM / 4);

    // 4) in_proj (bf16 MFMA): x half -> xraw, z half -> g = silu(z)
    mfma_inproj_kernel<<<dim3(kM / 128, 2 * kDI / 128), dim3(256), 0, stream>>>(
        tokb, wb, xraw, gbuf);

    // 5) causal conv + silu
    conv_silu_kernel<<<dim3(kM * kDI / 256), dim3(256), 0, stream>>>(xraw, conv_w, conv_b, xbuf);

    // 6) x_proj split-K (overwrites tokb/wb region with partials)
    xproj_splitk_kernel<<<dim3(kM / 64, kKS), dim3(256), 0, stream>>>(xbuf, x_proj_w, part);
    xproj_reduce_kernel<<<dim3(kM * kNX / 256), dim3(256), 0, stream>>>(part, xdbl);

    // 7) dt_proj + softplus
    dtproj_kernel<<<dim3(kM / 16, kDI / 256), dim3(256), 0, stream>>>(
        xdbl, dt_proj_w, dt_proj_b, dt);

    // 8) selective scan + gating + L-sum
    scan2_kernel<<<dim3(kB * 96), dim3(256), 0, stream>>>(
        dt, xbuf, gbuf, xdbl, A_log, Dvec, ysum);

    // 9) out = (ysum/L) @ out_proj_w.T
    final_kernel<<<dim3(kB * kDM / 4), dim3(256), 0, stream>>>(ysum, out_proj_w, out);
}

// Round 4
// 227.678 us; speedup vs baseline: 2.1213x; 2.1213x over previous
//
#include <hip/hip_runtime.h>
#include <math.h>

// Problem constants
constexpr int kB   = 4;
constexpr int kL   = 1024;
constexpr int kDM  = 768;
constexpr int kDI  = 1536;   // 2*kDM
constexpr int kDS  = 16;     // D_STATE
constexpr int kDTR = 48;     // DT_RANK
constexpr int kNX  = 80;     // DTR + 2*DS
constexpr int kM   = kB * kL; // 4096
constexpr int kLTXT = 128;

typedef __attribute__((ext_vector_type(8))) short bf16x8;
typedef __attribute__((ext_vector_type(4))) float f32x4;

__device__ inline unsigned short f2bf(float f) {
    unsigned u = __float_as_uint(f);
    u = (u + 0x7FFFu + ((u >> 16) & 1u)) >> 16;   // RNE
    return (unsigned short)u;
}

__device__ __forceinline__ void gl2lds16(const unsigned short* g, unsigned short* l) {
    __builtin_amdgcn_global_load_lds(
        (const __attribute__((address_space(1))) unsigned int*)g,
        (__attribute__((address_space(3))) unsigned int*)l, 16, 0, 0);
}

// ---------------------------------------------------------------------------
// txt[b][j] = b_txt[j] + sum_k text_tokens[b,0,k] * W_txt[j,k]
__global__ __launch_bounds__(256) void txt_kernel(
    const float* __restrict__ text, const float* __restrict__ Wt,
    const float* __restrict__ bt, float* __restrict__ txt)
{
    int gw = blockIdx.x * 4 + (threadIdx.x >> 6);
    int lane = threadIdx.x & 63;
    int b = gw / kDM;
    int j = gw - b * kDM;
    const float* trow = text + (size_t)b * kLTXT * kDM;
    const float* wrow = Wt + (size_t)j * kDM;
    float acc = 0.f;
    for (int k = lane; k < kDM; k += 64) acc = fmaf(trow[k], wrow[k], acc);
    #pragma unroll
    for (int o = 32; o; o >>= 1) acc += __shfl_xor(acc, o, 64);
    if (lane == 0) txt[gw] = acc + bt[j];
}

// ---------------------------------------------------------------------------
// tokens_bf16[m][k] = bf16(image[m][k] + txt[m/1024][k])
__global__ __launch_bounds__(256) void tokens_bf16_kernel(
    const float* __restrict__ img, const float* __restrict__ txt,
    unsigned short* __restrict__ tok)
{
    int i = blockIdx.x * 256 + threadIdx.x;        // over kM*kDM/4
    float4 a = ((const float4*)img)[i];
    int m = i / (kDM / 4);
    int k4 = i - m * (kDM / 4);
    float4 tv = ((const float4*)(txt + (size_t)(m >> 10) * kDM))[k4];
    ushort4 o;
    o.x = f2bf(a.x + tv.x); o.y = f2bf(a.y + tv.y);
    o.z = f2bf(a.z + tv.z); o.w = f2bf(a.w + tv.w);
    ((ushort4*)tok)[i] = o;
}

// ---------------------------------------------------------------------------
// cast in_proj_w (f32, [3072][768]) -> bf16
__global__ __launch_bounds__(256) void castw_kernel(
    const float* __restrict__ w, unsigned short* __restrict__ o, int n4)
{
    int i = blockIdx.x * 256 + threadIdx.x;
    if (i >= n4) return;
    float4 a = ((const float4*)w)[i];
    ushort4 v;
    v.x = f2bf(a.x); v.y = f2bf(a.y); v.z = f2bf(a.z); v.w = f2bf(a.w);
    ((ushort4*)o)[i] = v;
}

// ---------------------------------------------------------------------------
// bf16 MFMA GEMM for in_proj (global_load_lds width-16, double-buffered LDS).
// M=4096, N=3072, K=768. BM=BN=128, BK=32, 256 threads (4 waves, 2x2).
// n<1536 -> xout; n>=1536 -> gout = silu(v)
__global__ __launch_bounds__(256) void mfma_inproj_kernel(
    const unsigned short* __restrict__ A, const unsigned short* __restrict__ W,
    float* __restrict__ xout, float* __restrict__ gout)
{
    __shared__ unsigned short Asm[2][128][32];
    __shared__ unsigned short Wsm[2][128][32];
    const int t = threadIdx.x;
    const int lane = t & 63;
    const int wv = t >> 6;             // wave 0..3
    const int wr = wv >> 1, wc = wv & 1;
    const int m0 = blockIdx.x * 128;
    const int n0 = blockIdx.y * 128;

    const int srow = lane >> 2;          // 0..15
    const int scol = (lane & 3) * 8;     // bf16 elem 0,8,16,24
    const unsigned short* agp  = A + (size_t)(m0 + wv * 32 + srow) * kDM + scol;
    const unsigned short* agp2 = agp + 16 * kDM;
    const unsigned short* wgp  = W + (size_t)(n0 + wv * 32 + srow) * kDM + scol;
    const unsigned short* wgp2 = wgp + 16 * kDM;

    auto stage = [&](int buf, int k0) {
        gl2lds16(agp  + k0, &Asm[buf][wv * 32][0]);
        gl2lds16(agp2 + k0, &Asm[buf][wv * 32 + 16][0]);
        gl2lds16(wgp  + k0, &Wsm[buf][wv * 32][0]);
        gl2lds16(wgp2 + k0, &Wsm[buf][wv * 32 + 16][0]);
    };

    f32x4 acc[4][4] = {};
    const int fr = lane & 15;
    const int fk = (lane >> 4) * 8;

    stage(0, 0);
    __syncthreads();

    int buf = 0;
    for (int k0 = 0; k0 < kDM; k0 += 32) {
        if (k0 + 32 < kDM) stage(buf ^ 1, k0 + 32);
        bf16x8 af[4], wf[4];
        #pragma unroll
        for (int i = 0; i < 4; ++i)
            af[i] = *(const bf16x8*)&Asm[buf][wr * 64 + i * 16 + fr][fk];
        #pragma unroll
        for (int j = 0; j < 4; ++j)
            wf[j] = *(const bf16x8*)&Wsm[buf][wc * 64 + j * 16 + fr][fk];
        #pragma unroll
        for (int i = 0; i < 4; ++i)
            #pragma unroll
            for (int j = 0; j < 4; ++j)
                acc[i][j] = __builtin_amdgcn_mfma_f32_16x16x32_bf16(af[i], wf[j], acc[i][j], 0, 0, 0);
        __syncthreads();
        buf ^= 1;
    }

    const int erow = (lane >> 4) * 4;
    const int ecol = lane & 15;
    #pragma unroll
    for (int i = 0; i < 4; ++i) {
        #pragma unroll
        for (int j = 0; j < 4; ++j) {
            const int gn = n0 + wc * 64 + j * 16 + ecol;
            #pragma unroll
            for (int q = 0; q < 4; ++q) {
                const int gm = m0 + wr * 64 + i * 16 + erow + q;
                float v = acc[i][j][q];
                if (gn < kDI) {
                    xout[(size_t)gm * kDI + gn] = v;
                } else {
                    gout[(size_t)gm * kDI + (gn - kDI)] = v / (1.f + __expf(-v));
                }
            }
        }
    }
}

// ---------------------------------------------------------------------------
// x_proj split-K: part[ks][m][n] = sum_{k in seg ks} x[m][k] * W[n][k]
constexpr int kKS   = 8;
constexpr int kKSEG = kDI / kKS;   // 192

__global__ __launch_bounds__(256) void xproj_splitk_kernel(
    const float* __restrict__ A, const float* __restrict__ W,
    float* __restrict__ part)
{
    __shared__ float As[16][68];
    __shared__ float Ws[16][84];
    const int t = threadIdx.x;
    const int m0 = blockIdx.x * 64;
    const int kbase = blockIdx.y * kKSEG;
    const int lrow = t >> 2, lk4 = (t & 3) << 2;
    const int ci = (t & 15) << 2;      // 4 rows
    const int cj = (t >> 4) * 5;       // 5 cols (16*5 = 80)
    float acc[4][5] = {};
    const float* aptr = A + (size_t)(m0 + lrow) * kDI + kbase + lk4;

    for (int k0 = 0; k0 < kKSEG; k0 += 16) {
        float4 av = *(const float4*)(aptr + k0);
        if (k0) __syncthreads();
        As[lk4+0][lrow] = av.x; As[lk4+1][lrow] = av.y;
        As[lk4+2][lrow] = av.z; As[lk4+3][lrow] = av.w;
        #pragma unroll
        for (int i = 0; i < 5; ++i) {
            int idx = t + 256 * i;
            int n = idx % 80;
            int k = idx / 80;
            Ws[k][n] = W[(size_t)n * kDI + kbase + k0 + k];
        }
        __syncthreads();
        #pragma unroll
        for (int k = 0; k < 16; ++k) {
            const float4 a4 = *(const float4*)&As[k][ci];
            const float aa[4] = {a4.x, a4.y, a4.z, a4.w};
            float ww[5];
            #pragma unroll
            for (int j = 0; j < 5; ++j) ww[j] = Ws[k][cj + j];
            #pragma unroll
            for (int i = 0; i < 4; ++i)
                #pragma unroll
                for (int j = 0; j < 5; ++j)
                    acc[i][j] = fmaf(aa[i], ww[j], acc[i][j]);
        }
    }

    float* pbase = part + ((size_t)blockIdx.y * kM) * kNX;
    #pragma unroll
    for (int i = 0; i < 4; ++i)
        #pragma unroll
        for (int j = 0; j < 5; ++j)
            pbase[(size_t)(m0 + ci + i) * kNX + cj + j] = acc[i][j];
}

__global__ __launch_bounds__(256) void xproj_reduce_kernel(
    const float* __restrict__ part, float* __restrict__ xdbl)
{
    int i = blockIdx.x * 256 + threadIdx.x;    // over kM*kNX
    float s = 0.f;
    #pragma unroll
    for (int k = 0; k < kKS; ++k) s += part[(size_t)k * kM * kNX + i];
    xdbl[i] = s;
}

// ---------------------------------------------------------------------------
// dt_proj v2: dt[m][n] = softplus(dot(xdbl[m][:48], Wd[n][:]) + b[n])
// Block: 8 m-rows x 256 n-cols. W row per-thread in 48 VGPRs (L2-hot),
// A tile in LDS read as broadcast float4. ~70 VGPRs, no spill.
constexpr int kMR = 8;   // m-rows per block

__global__ __launch_bounds__(256) void dtproj2_kernel(
    const float* __restrict__ xdbl, const float* __restrict__ Wd,
    const float* __restrict__ bias, float* __restrict__ dt)
{
    __shared__ float As[kMR][52];              // 48 used, pad to 52
    const int t = threadIdx.x;
    const int m0 = blockIdx.x * kMR;
    const int n0 = blockIdx.y * 256;
    const int n = n0 + t;

    if (t < kMR * 12) {                        // 96 float4 loads
        int m = t / 12, c4 = (t % 12) * 4;
        *(float4*)&As[m][c4] = *(const float4*)&xdbl[(size_t)(m0 + m) * kNX + c4];
    }

    float4 w[12];
    const float* wrow = Wd + (size_t)n * kDTR;
    #pragma unroll
    for (int i = 0; i < 12; ++i) w[i] = *(const float4*)(wrow + i * 4);
    const float bn = bias[n];
    __syncthreads();

    float acc[kMR] = {};
    #pragma unroll
    for (int k4 = 0; k4 < 12; ++k4) {
        #pragma unroll
        for (int m = 0; m < kMR; ++m) {
            const float4 a4 = *(const float4*)&As[m][k4 * 4];  // LDS broadcast
            acc[m] = fmaf(a4.x, w[k4].x, acc[m]);
            acc[m] = fmaf(a4.y, w[k4].y, acc[m]);
            acc[m] = fmaf(a4.z, w[k4].z, acc[m]);
            acc[m] = fmaf(a4.w, w[k4].w, acc[m]);
        }
    }
    #pragma unroll
    for (int m = 0; m < kMR; ++m) {
        float v = acc[m] + bn;
        v = (v > 20.f) ? v : log1pf(__expf(v));
        dt[(size_t)(m0 + m) * kDI + n] = v;
    }
}

// ---------------------------------------------------------------------------
// causal depthwise conv (k=4) + SiLU, float4 over d
__global__ __launch_bounds__(256) void conv_silu_kernel(
    const float* __restrict__ xraw, const float* __restrict__ cw,
    const float* __restrict__ cb, float* __restrict__ xout)
{
    int i = blockIdx.x * 256 + threadIdx.x;     // over kM*kDI/4
    int d4 = i % (kDI / 4);
    int ml = i / (kDI / 4);
    int l = ml & (kL - 1);
    const int d = d4 * 4;
    float4 acc = *(const float4*)&cb[d];
    const float* base = xraw + (size_t)ml * kDI + d - 3 * (size_t)kDI;
    // weights for 4 channels: cw[d..d+3][0..3] = 16 consecutive floats
    float4 w0 = *(const float4*)&cw[(d + 0) * 4];
    float4 w1 = *(const float4*)&cw[(d + 1) * 4];
    float4 w2 = *(const float4*)&cw[(d + 2) * 4];
    float4 w3 = *(const float4*)&cw[(d + 3) * 4];
    const float wj[4][4] = {{w0.x, w1.x, w2.x, w3.x}, {w0.y, w1.y, w2.y, w3.y},
                            {w0.z, w1.z, w2.z, w3.z}, {w0.w, w1.w, w2.w, w3.w}};
    #pragma unroll
    for (int j = 0; j < 4; ++j) {
        if (l - 3 + j >= 0) {
            float4 xv = *(const float4*)(base + (size_t)j * kDI);
            acc.x = fmaf(xv.x, wj[j][0], acc.x);
            acc.y = fmaf(xv.y, wj[j][1], acc.y);
            acc.z = fmaf(xv.z, wj[j][2], acc.z);
            acc.w = fmaf(xv.w, wj[j][3], acc.w);
        }
    }
    acc.x /= (1.f + __expf(-acc.x));
    acc.y /= (1.f + __expf(-acc.y));
    acc.z /= (1.f + __expf(-acc.z));
    acc.w /= (1.f + __expf(-acc.w));
    *(float4*)&xout[(size_t)ml * kDI + d] = acc;
}

// ---------------------------------------------------------------------------
// Selective scan. Block = 256 threads = 16 channels x 16 states, one b.
constexpr int kT  = 64;          // steps per chunk
constexpr int kNC = kL / kT;     // 16 chunks

__global__ __launch_bounds__(256) void scan2_kernel(
    const float* __restrict__ dt, const float* __restrict__ x,
    const float* __restrict__ g, const float* __restrict__ xdbl,
    const float* __restrict__ A_log, const float* __restrict__ Dvec,
    float* __restrict__ ysum)
{
    __shared__ float dtS[2][kT][16];
    __shared__ float uS [2][kT][16];
    __shared__ float gS [2][kT][16];
    __shared__ float BS [2][kT][16];
    __shared__ float CS [2][kT][16];
    const int t = threadIdx.x;
    const int b  = blockIdx.x / 96;
    const int d0 = (blockIdx.x % 96) * 16;

    const int sl = t >> 2, sc = (t & 3) << 2;
    const float* dt_base = dt + ((size_t)b << 10) * kDI + d0;
    const float* x_base  = x  + ((size_t)b << 10) * kDI + d0;
    const float* g_base  = g  + ((size_t)b << 10) * kDI + d0;
    const float* bc_base = xdbl + ((size_t)b << 10) * kNX + kDTR;

    const int s = t & 15;     // state
    const int c = t >> 4;     // channel in block
    const int d = d0 + c;
    const float Aval = -__expf(A_log[d * kDS + s]);

    float4 r_dt, r_u, r_g, r_B, r_C;
    auto load_chunk = [&](int l0) {
        r_dt = *(const float4*)(dt_base + (size_t)(l0 + sl) * kDI + sc);
        r_u  = *(const float4*)(x_base  + (size_t)(l0 + sl) * kDI + sc);
        r_g  = *(const float4*)(g_base  + (size_t)(l0 + sl) * kDI + sc);
        r_B  = *(const float4*)(bc_base + (size_t)(l0 + sl) * kNX + sc);
        r_C  = *(const float4*)(bc_base + (size_t)(l0 + sl) * kNX + 16 + sc);
    };
    auto store_chunk = [&](int bf) {
        *(float4*)&dtS[bf][sl][sc] = r_dt;
        *(float4*)&uS [bf][sl][sc] = r_u;
        *(float4*)&gS [bf][sl][sc] = r_g;
        *(float4*)&BS [bf][sl][sc] = r_B;
        *(float4*)&CS [bf][sl][sc] = r_C;
    };

    load_chunk(0);
    store_chunk(0);
    __syncthreads();

    float h = 0.f, acc = 0.f, ug = 0.f;
    for (int ck = 0; ck < kNC; ++ck) {
        const int bu = ck & 1;
        if (ck + 1 < kNC) load_chunk((ck + 1) * kT);
        #pragma unroll 4
        for (int i = 0; i < kT; ++i) {
            const float dtv = dtS[bu][i][c];
            const float uv  = uS [bu][i][c];
            const float gv  = gS [bu][i][c];
            const float Bv  = BS [bu][i][s];
            const float Cv  = CS [bu][i][s];
            const float dA  = __expf(dtv * Aval);
            h   = fmaf(dA, h, dtv * uv * Bv);
            acc = fmaf(h * Cv, gv, acc);
            ug  = fmaf(uv, gv, ug);
        }
        if (ck + 1 < kNC) {
            __syncthreads();
            store_chunk(bu ^ 1);
            __syncthreads();
        }
    }

    #pragma unroll
    for (int o = 1; o < 16; o <<= 1) acc += __shfl_xor(acc, o, 64);
    if (s == 0) ysum[(size_t)b * kDI + d] = acc + Dvec[d] * ug;
}

// ---------------------------------------------------------------------------
// out[b][j] = (1/L) * sum_d ysum[b][d] * Wout[j][d]
__global__ __launch_bounds__(256) void final_kernel(
    const float* __restrict__ ysum, const float* __restrict__ Wout,
    float* __restrict__ out)
{
    int gw = blockIdx.x * 4 + (threadIdx.x >> 6);
    int lane = threadIdx.x & 63;
    int b = gw / kDM;
    int j = gw - b * kDM;
    const float* yrow = ysum + (size_t)b * kDI;
    const float* wrow = Wout + (size_t)j * kDI;
    float acc = 0.f;
    for (int k = lane; k < kDI; k += 64) acc = fmaf(yrow[k], wrow[k], acc);
    #pragma unroll
    for (int o = 32; o; o >>= 1) acc += __shfl_xor(acc, o, 64);
    if (lane == 0) out[gw] = acc * (1.f / (float)kL);
}

// ---------------------------------------------------------------------------
extern "C" void kernel_launch(void* const* d_in, const int* in_sizes, int n_in,
                              void* d_out, int out_size, void* d_ws, size_t ws_size,
                              hipStream_t stream)
{
    const float* image_tokens = (const float*)d_in[0];
    const float* text_tokens  = (const float*)d_in[1];
    const float* W_txt        = (const float*)d_in[2];
    const float* b_txt        = (const float*)d_in[3];
    const float* in_proj_w    = (const float*)d_in[4];
    const float* conv_w       = (const float*)d_in[5];
    const float* conv_b       = (const float*)d_in[6];
    const float* x_proj_w     = (const float*)d_in[7];
    const float* dt_proj_w    = (const float*)d_in[8];
    const float* dt_proj_b    = (const float*)d_in[9];
    const float* A_log        = (const float*)d_in[10];
    const float* Dvec         = (const float*)d_in[11];
    const float* out_proj_w   = (const float*)d_in[12];
    float* out = (float*)d_out;

    // workspace layout (bytes, all 256B-aligned)
    char* p = (char*)d_ws;
    float* txt = (float*)p;                       p += 12288;
    unsigned short* tokb = (unsigned short*)p;    p += (size_t)kM * kDM * 2;       // 6.3 MB
    unsigned short* wb   = (unsigned short*)p;    p += (size_t)2 * kDI * kDM * 2;  // 4.7 MB
    float* xraw = (float*)p;                      p += (size_t)kM * kDI * 4;       // 25.2 MB (reused as dt)
    float* gbuf = (float*)p;                      p += (size_t)kM * kDI * 4;       // 25.2 MB
    float* xbuf = (float*)p;                      p += (size_t)kM * kDI * 4;       // 25.2 MB
    float* xdbl = (float*)p;                      p += (size_t)kM * kNX * 4;       // 1.3 MB
    float* ysum = (float*)p;                      p += (size_t)kB * kDI * 4;
    float* dt = xraw;                 // xraw dead after conv
    float* part = (float*)tokb;       // 10.5 MB; tokb+wb dead after in_proj

    // 1) txt projection
    txt_kernel<<<dim3(kB * kDM / 4), dim3(256), 0, stream>>>(text_tokens, W_txt, b_txt, txt);

    // 2) tokens = bf16(image + txt)
    tokens_bf16_kernel<<<dim3(kM * kDM / 4 / 256), dim3(256), 0, stream>>>(image_tokens, txt, tokb);

    // 3) cast in_proj_w to bf16
    castw_kernel<<<dim3((2 * kDI * kDM / 4 + 255) / 256), dim3(256), 0, stream>>>(
        in_proj_w, wb, 2 * kDI * kDM / 4);

    // 4) in_proj (bf16 MFMA): x half -> xraw, z half -> g = silu(z)
    mfma_inproj_kernel<<<dim3(kM / 128, 2 * kDI / 128), dim3(256), 0, stream>>>(
        tokb, wb, xraw, gbuf);

    // 5) causal conv + silu (float4)
    conv_silu_kernel<<<dim3(kM * kDI / 4 / 256), dim3(256), 0, stream>>>(
        xraw, conv_w, conv_b, xbuf);

    // 6) x_proj split-K
    xproj_splitk_kernel<<<dim3(kM / 64, kKS), dim3(256), 0, stream>>>(xbuf, x_proj_w, part);
    xproj_reduce_kernel<<<dim3(kM * kNX / 256), dim3(256), 0, stream>>>(part, xdbl);

    // 7) dt_proj + softplus (v2: no spill, write-bound)
    dtproj2_kernel<<<dim3(kM / kMR, kDI / 256), dim3(256), 0, stream>>>(
        xdbl, dt_proj_w, dt_proj_b, dt);

    // 8) selective scan + gating + L-sum
    scan2_kernel<<<dim3(kB * 96), dim3(256), 0, stream>>>(
        dt, xbuf, gbuf, xdbl, A_log, Dvec, ysum);

    // 9) out = (ysum/L) @ out_proj_w.T
    final_kernel<<<dim3(kB * kDM / 4), dim3(256), 0, stream>>>(ysum, out_proj_w, out);
}

// Round 5
// 221.218 us; speedup vs baseline: 2.1833x; 1.0292x over previous
//
#include <hip/hip_runtime.h>
#include <math.h>

// Problem constants
constexpr int kB   = 4;
constexpr int kL   = 1024;
constexpr int kDM  = 768;
constexpr int kDI  = 1536;   // 2*kDM
constexpr int kDS  = 16;     // D_STATE
constexpr int kDTR = 48;     // DT_RANK
constexpr int kNX  = 80;     // DTR + 2*DS
constexpr int kM   = kB * kL; // 4096
constexpr int kLTXT = 128;

typedef __attribute__((ext_vector_type(8))) short bf16x8;
typedef __attribute__((ext_vector_type(4))) float f32x4;

__device__ inline unsigned short f2bf(float f) {
    unsigned u = __float_as_uint(f);
    u = (u + 0x7FFFu + ((u >> 16) & 1u)) >> 16;   // RNE
    return (unsigned short)u;
}

__device__ __forceinline__ void gl2lds16(const unsigned short* g, unsigned short* l) {
    __builtin_amdgcn_global_load_lds(
        (const __attribute__((address_space(1))) unsigned int*)g,
        (__attribute__((address_space(3))) unsigned int*)l, 16, 0, 0);
}

// ---------------------------------------------------------------------------
// txt[b][j] = b_txt[j] + sum_k text_tokens[b,0,k] * W_txt[j,k]
__global__ __launch_bounds__(256) void txt_kernel(
    const float* __restrict__ text, const float* __restrict__ Wt,
    const float* __restrict__ bt, float* __restrict__ txt)
{
    int gw = blockIdx.x * 4 + (threadIdx.x >> 6);
    int lane = threadIdx.x & 63;
    int b = gw / kDM;
    int j = gw - b * kDM;
    const float* trow = text + (size_t)b * kLTXT * kDM;
    const float* wrow = Wt + (size_t)j * kDM;
    float acc = 0.f;
    for (int k = lane; k < kDM; k += 64) acc = fmaf(trow[k], wrow[k], acc);
    #pragma unroll
    for (int o = 32; o; o >>= 1) acc += __shfl_xor(acc, o, 64);
    if (lane == 0) txt[gw] = acc + bt[j];
}

// ---------------------------------------------------------------------------
// tokens_bf16[m][k] = bf16(image[m][k] + txt[m/1024][k])
__global__ __launch_bounds__(256) void tokens_bf16_kernel(
    const float* __restrict__ img, const float* __restrict__ txt,
    unsigned short* __restrict__ tok)
{
    int i = blockIdx.x * 256 + threadIdx.x;        // over kM*kDM/4
    float4 a = ((const float4*)img)[i];
    int m = i / (kDM / 4);
    int k4 = i - m * (kDM / 4);
    float4 tv = ((const float4*)(txt + (size_t)(m >> 10) * kDM))[k4];
    ushort4 o;
    o.x = f2bf(a.x + tv.x); o.y = f2bf(a.y + tv.y);
    o.z = f2bf(a.z + tv.z); o.w = f2bf(a.w + tv.w);
    ((ushort4*)tok)[i] = o;
}

// ---------------------------------------------------------------------------
// cast in_proj_w (f32, [3072][768]) -> bf16
__global__ __launch_bounds__(256) void castw_kernel(
    const float* __restrict__ w, unsigned short* __restrict__ o, int n4)
{
    int i = blockIdx.x * 256 + threadIdx.x;
    if (i >= n4) return;
    float4 a = ((const float4*)w)[i];
    ushort4 v;
    v.x = f2bf(a.x); v.y = f2bf(a.y); v.z = f2bf(a.z); v.w = f2bf(a.w);
    ((ushort4*)o)[i] = v;
}

// ---------------------------------------------------------------------------
// bf16 MFMA GEMM for in_proj (global_load_lds width-16, double-buffered LDS).
// M=4096, N=3072, K=768. BM=BN=128, BK=32, 256 threads (4 waves, 2x2).
// n<1536 -> xout; n>=1536 -> gout = silu(v)
__global__ __launch_bounds__(256) void mfma_inproj_kernel(
    const unsigned short* __restrict__ A, const unsigned short* __restrict__ W,
    float* __restrict__ xout, float* __restrict__ gout)
{
    __shared__ unsigned short Asm[2][128][32];
    __shared__ unsigned short Wsm[2][128][32];
    const int t = threadIdx.x;
    const int lane = t & 63;
    const int wv = t >> 6;             // wave 0..3
    const int wr = wv >> 1, wc = wv & 1;
    const int m0 = blockIdx.x * 128;
    const int n0 = blockIdx.y * 128;

    const int srow = lane >> 2;          // 0..15
    const int scol = (lane & 3) * 8;     // bf16 elem 0,8,16,24
    const unsigned short* agp  = A + (size_t)(m0 + wv * 32 + srow) * kDM + scol;
    const unsigned short* agp2 = agp + 16 * kDM;
    const unsigned short* wgp  = W + (size_t)(n0 + wv * 32 + srow) * kDM + scol;
    const unsigned short* wgp2 = wgp + 16 * kDM;

    auto stage = [&](int buf, int k0) {
        gl2lds16(agp  + k0, &Asm[buf][wv * 32][0]);
        gl2lds16(agp2 + k0, &Asm[buf][wv * 32 + 16][0]);
        gl2lds16(wgp  + k0, &Wsm[buf][wv * 32][0]);
        gl2lds16(wgp2 + k0, &Wsm[buf][wv * 32 + 16][0]);
    };

    f32x4 acc[4][4] = {};
    const int fr = lane & 15;
    const int fk = (lane >> 4) * 8;

    stage(0, 0);
    __syncthreads();

    int buf = 0;
    for (int k0 = 0; k0 < kDM; k0 += 32) {
        if (k0 + 32 < kDM) stage(buf ^ 1, k0 + 32);
        bf16x8 af[4], wf[4];
        #pragma unroll
        for (int i = 0; i < 4; ++i)
            af[i] = *(const bf16x8*)&Asm[buf][wr * 64 + i * 16 + fr][fk];
        #pragma unroll
        for (int j = 0; j < 4; ++j)
            wf[j] = *(const bf16x8*)&Wsm[buf][wc * 64 + j * 16 + fr][fk];
        #pragma unroll
        for (int i = 0; i < 4; ++i)
            #pragma unroll
            for (int j = 0; j < 4; ++j)
                acc[i][j] = __builtin_amdgcn_mfma_f32_16x16x32_bf16(af[i], wf[j], acc[i][j], 0, 0, 0);
        __syncthreads();
        buf ^= 1;
    }

    const int erow = (lane >> 4) * 4;
    const int ecol = lane & 15;
    #pragma unroll
    for (int i = 0; i < 4; ++i) {
        #pragma unroll
        for (int j = 0; j < 4; ++j) {
            const int gn = n0 + wc * 64 + j * 16 + ecol;
            #pragma unroll
            for (int q = 0; q < 4; ++q) {
                const int gm = m0 + wr * 64 + i * 16 + erow + q;
                float v = acc[i][j][q];
                if (gn < kDI) {
                    xout[(size_t)gm * kDI + gn] = v;
                } else {
                    gout[(size_t)gm * kDI + (gn - kDI)] = v / (1.f + __expf(-v));
                }
            }
        }
    }
}

// ---------------------------------------------------------------------------
// x_proj split-K: part[ks][m][n] = sum_{k in seg ks} x[m][k] * W[n][k]
constexpr int kKS   = 8;
constexpr int kKSEG = kDI / kKS;   // 192

__global__ __launch_bounds__(256) void xproj_splitk_kernel(
    const float* __restrict__ A, const float* __restrict__ W,
    float* __restrict__ part)
{
    __shared__ float As[16][68];
    __shared__ float Ws[16][84];
    const int t = threadIdx.x;
    const int m0 = blockIdx.x * 64;
    const int kbase = blockIdx.y * kKSEG;
    const int lrow = t >> 2, lk4 = (t & 3) << 2;
    const int ci = (t & 15) << 2;      // 4 rows
    const int cj = (t >> 4) * 5;       // 5 cols (16*5 = 80)
    float acc[4][5] = {};
    const float* aptr = A + (size_t)(m0 + lrow) * kDI + kbase + lk4;

    for (int k0 = 0; k0 < kKSEG; k0 += 16) {
        float4 av = *(const float4*)(aptr + k0);
        if (k0) __syncthreads();
        As[lk4+0][lrow] = av.x; As[lk4+1][lrow] = av.y;
        As[lk4+2][lrow] = av.z; As[lk4+3][lrow] = av.w;
        #pragma unroll
        for (int i = 0; i < 5; ++i) {
            int idx = t + 256 * i;
            int n = idx % 80;
            int k = idx / 80;
            Ws[k][n] = W[(size_t)n * kDI + kbase + k0 + k];
        }
        __syncthreads();
        #pragma unroll
        for (int k = 0; k < 16; ++k) {
            const float4 a4 = *(const float4*)&As[k][ci];
            const float aa[4] = {a4.x, a4.y, a4.z, a4.w};
            float ww[5];
            #pragma unroll
            for (int j = 0; j < 5; ++j) ww[j] = Ws[k][cj + j];
            #pragma unroll
            for (int i = 0; i < 4; ++i)
                #pragma unroll
                for (int j = 0; j < 5; ++j)
                    acc[i][j] = fmaf(aa[i], ww[j], acc[i][j]);
        }
    }

    float* pbase = part + ((size_t)blockIdx.y * kM) * kNX;
    #pragma unroll
    for (int i = 0; i < 4; ++i)
        #pragma unroll
        for (int j = 0; j < 5; ++j)
            pbase[(size_t)(m0 + ci + i) * kNX + cj + j] = acc[i][j];
}

__global__ __launch_bounds__(256) void xproj_reduce_kernel(
    const float* __restrict__ part, float* __restrict__ xdbl)
{
    int i = blockIdx.x * 256 + threadIdx.x;    // over kM*kNX
    float s = 0.f;
    #pragma unroll
    for (int k = 0; k < kKS; ++k) s += part[(size_t)k * kM * kNX + i];
    xdbl[i] = s;
}

// ---------------------------------------------------------------------------
// causal depthwise conv (k=4) + SiLU, float4 over d
__global__ __launch_bounds__(256) void conv_silu_kernel(
    const float* __restrict__ xraw, const float* __restrict__ cw,
    const float* __restrict__ cb, float* __restrict__ xout)
{
    int i = blockIdx.x * 256 + threadIdx.x;     // over kM*kDI/4
    int d4 = i % (kDI / 4);
    int ml = i / (kDI / 4);
    int l = ml & (kL - 1);
    const int d = d4 * 4;
    float4 acc = *(const float4*)&cb[d];
    const float* base = xraw + (size_t)ml * kDI + d - 3 * (size_t)kDI;
    float4 w0 = *(const float4*)&cw[(d + 0) * 4];
    float4 w1 = *(const float4*)&cw[(d + 1) * 4];
    float4 w2 = *(const float4*)&cw[(d + 2) * 4];
    float4 w3 = *(const float4*)&cw[(d + 3) * 4];
    const float wj[4][4] = {{w0.x, w1.x, w2.x, w3.x}, {w0.y, w1.y, w2.y, w3.y},
                            {w0.z, w1.z, w2.z, w3.z}, {w0.w, w1.w, w2.w, w3.w}};
    #pragma unroll
    for (int j = 0; j < 4; ++j) {
        if (l - 3 + j >= 0) {
            float4 xv = *(const float4*)(base + (size_t)j * kDI);
            acc.x = fmaf(xv.x, wj[j][0], acc.x);
            acc.y = fmaf(xv.y, wj[j][1], acc.y);
            acc.z = fmaf(xv.z, wj[j][2], acc.z);
            acc.w = fmaf(xv.w, wj[j][3], acc.w);
        }
    }
    acc.x /= (1.f + __expf(-acc.x));
    acc.y /= (1.f + __expf(-acc.y));
    acc.z /= (1.f + __expf(-acc.z));
    acc.w /= (1.f + __expf(-acc.w));
    *(float4*)&xout[(size_t)ml * kDI + d] = acc;
}

// ---------------------------------------------------------------------------
// Selective scan v3 with FUSED dt_proj.
// Block = 256 threads = 16 channels x 16 states, one (b, d0) slice.
// Stages full xdbl rows [64][80]; computes dt = softplus(dtr @ Wd^T + b)
// per chunk in-block (mini-GEMM), never materializing dt in HBM.
constexpr int kT  = 64;          // steps per chunk
constexpr int kNC = kL / kT;     // 16 chunks
constexpr int kXP = 84;          // xdS row pad (bank-spread for 4-row groups)

__global__ __launch_bounds__(256) void scan3_kernel(
    const float* __restrict__ x, const float* __restrict__ g,
    const float* __restrict__ xdbl, const float* __restrict__ Wd,
    const float* __restrict__ dt_bias,
    const float* __restrict__ A_log, const float* __restrict__ Dvec,
    float* __restrict__ ysum)
{
    __shared__ float xdS[2][kT][kXP];   // full xdbl rows (dtr | B | C)
    __shared__ float uS [2][kT][16];
    __shared__ float gS [2][kT][16];
    __shared__ float dtS[2][kT][17];    // computed dt, padded
    const int t = threadIdx.x;
    const int b  = blockIdx.x / 96;
    const int d0 = (blockIdx.x % 96) * 16;

    // ---- staging maps
    const int sl = t >> 2, sc = (t & 3) << 2;              // u/g: [64][16]
    const float* x_base  = x  + ((size_t)b << 10) * kDI + d0;
    const float* g_base  = g  + ((size_t)b << 10) * kDI + d0;
    const float* xd_base = xdbl + ((size_t)b << 10) * kNX;

    // ---- scan thread identity
    const int s = t & 15;     // state
    const int c = t >> 4;     // channel in block
    const int d = d0 + c;
    const float Aval = -__expf(A_log[d * kDS + s]);

    // ---- dt-compute identity: thread (cc = t&15 channel, ii = t>>4 row group)
    const int cc = t & 15, ii = t >> 4;
    float4 wreg[12];
    {
        const float* wrow = Wd + (size_t)(d0 + cc) * kDTR;
        #pragma unroll
        for (int i = 0; i < 12; ++i) wreg[i] = *(const float4*)(wrow + i * 4);
    }
    const float bn = dt_bias[d0 + cc];

    float4 r_u, r_g, r_xd[5];
    auto load_chunk = [&](int l0) {
        r_u = *(const float4*)(x_base + (size_t)(l0 + sl) * kDI + sc);
        r_g = *(const float4*)(g_base + (size_t)(l0 + sl) * kDI + sc);
        #pragma unroll
        for (int j = 0; j < 5; ++j) {
            int idx = t + 256 * j;           // 1280 float4 = [64][80]
            int row = idx / 20, col4 = idx % 20;
            r_xd[j] = *(const float4*)(xd_base + (size_t)(l0 + row) * kNX + col4 * 4);
        }
    };
    auto store_chunk = [&](int bf) {
        *(float4*)&uS[bf][sl][sc] = r_u;
        *(float4*)&gS[bf][sl][sc] = r_g;
        #pragma unroll
        for (int j = 0; j < 5; ++j) {
            int idx = t + 256 * j;
            int row = idx / 20, col4 = idx % 20;
            *(float4*)&xdS[bf][row][col4 * 4] = r_xd[j];
        }
    };
    auto compute_dt = [&](int bf) {
        #pragma unroll
        for (int q = 0; q < 4; ++q) {
            const int i = ii * 4 + q;
            float a = bn;
            #pragma unroll
            for (int k4 = 0; k4 < 12; ++k4) {
                const float4 xv = *(const float4*)&xdS[bf][i][k4 * 4];
                a = fmaf(xv.x, wreg[k4].x, a);
                a = fmaf(xv.y, wreg[k4].y, a);
                a = fmaf(xv.z, wreg[k4].z, a);
                a = fmaf(xv.w, wreg[k4].w, a);
            }
            a = (a > 20.f) ? a : log1pf(__expf(a));     // softplus
            dtS[bf][i][cc] = a;
        }
    };

    load_chunk(0);
    store_chunk(0);
    __syncthreads();
    compute_dt(0);
    __syncthreads();

    float h = 0.f, acc = 0.f, ug = 0.f;
    for (int ck = 0; ck < kNC; ++ck) {
        const int bu = ck & 1;
        if (ck + 1 < kNC) load_chunk((ck + 1) * kT);
        #pragma unroll 4
        for (int i = 0; i < kT; ++i) {
            const float dtv = dtS[bu][i][c];
            const float uv  = uS [bu][i][c];
            const float gv  = gS [bu][i][c];
            const float Bv  = xdS[bu][i][kDTR + s];
            const float Cv  = xdS[bu][i][kDTR + 16 + s];
            const float dA  = __expf(dtv * Aval);
            h   = fmaf(dA, h, dtv * uv * Bv);
            acc = fmaf(h * Cv, gv, acc);
            ug  = fmaf(uv, gv, ug);
        }
        if (ck + 1 < kNC) {
            store_chunk(bu ^ 1);     // other buffer: no overlap with readers of bu
            __syncthreads();
            compute_dt(bu ^ 1);
            __syncthreads();
        }
    }

    #pragma unroll
    for (int o = 1; o < 16; o <<= 1) acc += __shfl_xor(acc, o, 64);
    if (s == 0) ysum[(size_t)b * kDI + d] = acc + Dvec[d] * ug;
}

// ---------------------------------------------------------------------------
// out[b][j] = (1/L) * sum_d ysum[b][d] * Wout[j][d]
__global__ __launch_bounds__(256) void final_kernel(
    const float* __restrict__ ysum, const float* __restrict__ Wout,
    float* __restrict__ out)
{
    int gw = blockIdx.x * 4 + (threadIdx.x >> 6);
    int lane = threadIdx.x & 63;
    int b = gw / kDM;
    int j = gw - b * kDM;
    const float* yrow = ysum + (size_t)b * kDI;
    const float* wrow = Wout + (size_t)j * kDI;
    float acc = 0.f;
    for (int k = lane; k < kDI; k += 64) acc = fmaf(yrow[k], wrow[k], acc);
    #pragma unroll
    for (int o = 32; o; o >>= 1) acc += __shfl_xor(acc, o, 64);
    if (lane == 0) out[gw] = acc * (1.f / (float)kL);
}

// ---------------------------------------------------------------------------
extern "C" void kernel_launch(void* const* d_in, const int* in_sizes, int n_in,
                              void* d_out, int out_size, void* d_ws, size_t ws_size,
                              hipStream_t stream)
{
    const float* image_tokens = (const float*)d_in[0];
    const float* text_tokens  = (const float*)d_in[1];
    const float* W_txt        = (const float*)d_in[2];
    const float* b_txt        = (const float*)d_in[3];
    const float* in_proj_w    = (const float*)d_in[4];
    const float* conv_w       = (const float*)d_in[5];
    const float* conv_b       = (const float*)d_in[6];
    const float* x_proj_w     = (const float*)d_in[7];
    const float* dt_proj_w    = (const float*)d_in[8];
    const float* dt_proj_b    = (const float*)d_in[9];
    const float* A_log        = (const float*)d_in[10];
    const float* Dvec         = (const float*)d_in[11];
    const float* out_proj_w   = (const float*)d_in[12];
    float* out = (float*)d_out;

    // workspace layout (bytes, all 256B-aligned)
    char* p = (char*)d_ws;
    float* txt = (float*)p;                       p += 12288;
    unsigned short* tokb = (unsigned short*)p;    p += (size_t)kM * kDM * 2;       // 6.3 MB
    unsigned short* wb   = (unsigned short*)p;    p += (size_t)2 * kDI * kDM * 2;  // 4.7 MB
    float* xraw = (float*)p;                      p += (size_t)kM * kDI * 4;       // 25.2 MB
    float* gbuf = (float*)p;                      p += (size_t)kM * kDI * 4;       // 25.2 MB
    float* xbuf = (float*)p;                      p += (size_t)kM * kDI * 4;       // 25.2 MB
    float* xdbl = (float*)p;                      p += (size_t)kM * kNX * 4;       // 1.3 MB
    float* ysum = (float*)p;                      p += (size_t)kB * kDI * 4;
    float* part = (float*)tokb;       // 10.5 MB; tokb+wb dead after in_proj

    // 1) txt projection
    txt_kernel<<<dim3(kB * kDM / 4), dim3(256), 0, stream>>>(text_tokens, W_txt, b_txt, txt);

    // 2) tokens = bf16(image + txt)
    tokens_bf16_kernel<<<dim3(kM * kDM / 4 / 256), dim3(256), 0, stream>>>(image_tokens, txt, tokb);

    // 3) cast in_proj_w to bf16
    castw_kernel<<<dim3((2 * kDI * kDM / 4 + 255) / 256), dim3(256), 0, stream>>>(
        in_proj_w, wb, 2 * kDI * kDM / 4);

    // 4) in_proj (bf16 MFMA): x half -> xraw, z half -> g = silu(z)
    mfma_inproj_kernel<<<dim3(kM / 128, 2 * kDI / 128), dim3(256), 0, stream>>>(
        tokb, wb, xraw, gbuf);

    // 5) causal conv + silu (float4)
    conv_silu_kernel<<<dim3(kM * kDI / 4 / 256), dim3(256), 0, stream>>>(
        xraw, conv_w, conv_b, xbuf);

    // 6) x_proj split-K
    xproj_splitk_kernel<<<dim3(kM / 64, kKS), dim3(256), 0, stream>>>(xbuf, x_proj_w, part);
    xproj_reduce_kernel<<<dim3(kM * kNX / 256), dim3(256), 0, stream>>>(part, xdbl);

    // 7) selective scan with fused dt_proj + gating + L-sum
    scan3_kernel<<<dim3(kB * 96), dim3(256), 0, stream>>>(
        xbuf, gbuf, xdbl, dt_proj_w, dt_proj_b, A_log, Dvec, ysum);

    // 8) out = (ysum/L) @ out_proj_w.T
    final_kernel<<<dim3(kB * kDM / 4), dim3(256), 0, stream>>>(ysum, out_proj_w, out);
}

// Round 6
// 207.235 us; speedup vs baseline: 2.3306x; 1.0675x over previous
//
#include <hip/hip_runtime.h>
#include <math.h>

// Problem constants
constexpr int kB   = 4;
constexpr int kL   = 1024;
constexpr int kDM  = 768;
constexpr int kDI  = 1536;   // 2*kDM
constexpr int kDS  = 16;     // D_STATE
constexpr int kDTR = 48;     // DT_RANK
constexpr int kNX  = 80;     // DTR + 2*DS
constexpr int kM   = kB * kL; // 4096
constexpr int kLTXT = 128;

typedef __attribute__((ext_vector_type(8))) short bf16x8;
typedef __attribute__((ext_vector_type(4))) float f32x4;

__device__ inline unsigned short f2bf(float f) {
    unsigned u = __float_as_uint(f);
    u = (u + 0x7FFFu + ((u >> 16) & 1u)) >> 16;   // RNE
    return (unsigned short)u;
}

__device__ __forceinline__ void gl2lds16(const unsigned short* g, unsigned short* l) {
    __builtin_amdgcn_global_load_lds(
        (const __attribute__((address_space(1))) unsigned int*)g,
        (__attribute__((address_space(3))) unsigned int*)l, 16, 0, 0);
}

// ---------------------------------------------------------------------------
// txt[b][j] = b_txt[j] + sum_k text_tokens[b,0,k] * W_txt[j,k]
__global__ __launch_bounds__(256) void txt_kernel(
    const float* __restrict__ text, const float* __restrict__ Wt,
    const float* __restrict__ bt, float* __restrict__ txt)
{
    int gw = blockIdx.x * 4 + (threadIdx.x >> 6);
    int lane = threadIdx.x & 63;
    int b = gw / kDM;
    int j = gw - b * kDM;
    const float* trow = text + (size_t)b * kLTXT * kDM;
    const float* wrow = Wt + (size_t)j * kDM;
    float acc = 0.f;
    for (int k = lane; k < kDM; k += 64) acc = fmaf(trow[k], wrow[k], acc);
    #pragma unroll
    for (int o = 32; o; o >>= 1) acc += __shfl_xor(acc, o, 64);
    if (lane == 0) txt[gw] = acc + bt[j];
}

// ---------------------------------------------------------------------------
// tokens_bf16[m][k] = bf16(image[m][k] + txt[m/1024][k])
__global__ __launch_bounds__(256) void tokens_bf16_kernel(
    const float* __restrict__ img, const float* __restrict__ txt,
    unsigned short* __restrict__ tok)
{
    int i = blockIdx.x * 256 + threadIdx.x;        // over kM*kDM/4
    float4 a = ((const float4*)img)[i];
    int m = i / (kDM / 4);
    int k4 = i - m * (kDM / 4);
    float4 tv = ((const float4*)(txt + (size_t)(m >> 10) * kDM))[k4];
    ushort4 o;
    o.x = f2bf(a.x + tv.x); o.y = f2bf(a.y + tv.y);
    o.z = f2bf(a.z + tv.z); o.w = f2bf(a.w + tv.w);
    ((ushort4*)tok)[i] = o;
}

// ---------------------------------------------------------------------------
// cast in_proj_w (f32, [3072][768]) -> bf16
__global__ __launch_bounds__(256) void castw_kernel(
    const float* __restrict__ w, unsigned short* __restrict__ o, int n4)
{
    int i = blockIdx.x * 256 + threadIdx.x;
    if (i >= n4) return;
    float4 a = ((const float4*)w)[i];
    ushort4 v;
    v.x = f2bf(a.x); v.y = f2bf(a.y); v.z = f2bf(a.z); v.w = f2bf(a.w);
    ((ushort4*)o)[i] = v;
}

// ---------------------------------------------------------------------------
// bf16 MFMA GEMM for in_proj (global_load_lds width-16, double-buffered LDS).
// M=4096, N=3072, K=768. BM=BN=128, BK=32, 256 threads (4 waves, 2x2).
// n<1536 -> xout; n>=1536 -> gout = silu(v)
__global__ __launch_bounds__(256) void mfma_inproj_kernel(
    const unsigned short* __restrict__ A, const unsigned short* __restrict__ W,
    float* __restrict__ xout, float* __restrict__ gout)
{
    __shared__ unsigned short Asm[2][128][32];
    __shared__ unsigned short Wsm[2][128][32];
    const int t = threadIdx.x;
    const int lane = t & 63;
    const int wv = t >> 6;             // wave 0..3
    const int wr = wv >> 1, wc = wv & 1;
    const int m0 = blockIdx.x * 128;
    const int n0 = blockIdx.y * 128;

    const int srow = lane >> 2;          // 0..15
    const int scol = (lane & 3) * 8;     // bf16 elem 0,8,16,24
    const unsigned short* agp  = A + (size_t)(m0 + wv * 32 + srow) * kDM + scol;
    const unsigned short* agp2 = agp + 16 * kDM;
    const unsigned short* wgp  = W + (size_t)(n0 + wv * 32 + srow) * kDM + scol;
    const unsigned short* wgp2 = wgp + 16 * kDM;

    auto stage = [&](int buf, int k0) {
        gl2lds16(agp  + k0, &Asm[buf][wv * 32][0]);
        gl2lds16(agp2 + k0, &Asm[buf][wv * 32 + 16][0]);
        gl2lds16(wgp  + k0, &Wsm[buf][wv * 32][0]);
        gl2lds16(wgp2 + k0, &Wsm[buf][wv * 32 + 16][0]);
    };

    f32x4 acc[4][4] = {};
    const int fr = lane & 15;
    const int fk = (lane >> 4) * 8;

    stage(0, 0);
    __syncthreads();

    int buf = 0;
    for (int k0 = 0; k0 < kDM; k0 += 32) {
        if (k0 + 32 < kDM) stage(buf ^ 1, k0 + 32);
        bf16x8 af[4], wf[4];
        #pragma unroll
        for (int i = 0; i < 4; ++i)
            af[i] = *(const bf16x8*)&Asm[buf][wr * 64 + i * 16 + fr][fk];
        #pragma unroll
        for (int j = 0; j < 4; ++j)
            wf[j] = *(const bf16x8*)&Wsm[buf][wc * 64 + j * 16 + fr][fk];
        #pragma unroll
        for (int i = 0; i < 4; ++i)
            #pragma unroll
            for (int j = 0; j < 4; ++j)
                acc[i][j] = __builtin_amdgcn_mfma_f32_16x16x32_bf16(af[i], wf[j], acc[i][j], 0, 0, 0);
        __syncthreads();
        buf ^= 1;
    }

    const int erow = (lane >> 4) * 4;
    const int ecol = lane & 15;
    #pragma unroll
    for (int i = 0; i < 4; ++i) {
        #pragma unroll
        for (int j = 0; j < 4; ++j) {
            const int gn = n0 + wc * 64 + j * 16 + ecol;
            #pragma unroll
            for (int q = 0; q < 4; ++q) {
                const int gm = m0 + wr * 64 + i * 16 + erow + q;
                float v = acc[i][j][q];
                if (gn < kDI) {
                    xout[(size_t)gm * kDI + gn] = v;
                } else {
                    gout[(size_t)gm * kDI + (gn - kDI)] = v / (1.f + __expf(-v));
                }
            }
        }
    }
}

// ---------------------------------------------------------------------------
// x_proj split-K: part[ks][m][n] = sum_{k in seg ks} x[m][k] * W[n][k]
constexpr int kKS   = 8;
constexpr int kKSEG = kDI / kKS;   // 192

__global__ __launch_bounds__(256) void xproj_splitk_kernel(
    const float* __restrict__ A, const float* __restrict__ W,
    float* __restrict__ part)
{
    __shared__ float As[16][68];
    __shared__ float Ws[16][84];
    const int t = threadIdx.x;
    const int m0 = blockIdx.x * 64;
    const int kbase = blockIdx.y * kKSEG;
    const int lrow = t >> 2, lk4 = (t & 3) << 2;
    const int ci = (t & 15) << 2;      // 4 rows
    const int cj = (t >> 4) * 5;       // 5 cols (16*5 = 80)
    float acc[4][5] = {};
    const float* aptr = A + (size_t)(m0 + lrow) * kDI + kbase + lk4;

    for (int k0 = 0; k0 < kKSEG; k0 += 16) {
        float4 av = *(const float4*)(aptr + k0);
        if (k0) __syncthreads();
        As[lk4+0][lrow] = av.x; As[lk4+1][lrow] = av.y;
        As[lk4+2][lrow] = av.z; As[lk4+3][lrow] = av.w;
        #pragma unroll
        for (int i = 0; i < 5; ++i) {
            int idx = t + 256 * i;
            int n = idx % 80;
            int k = idx / 80;
            Ws[k][n] = W[(size_t)n * kDI + kbase + k0 + k];
        }
        __syncthreads();
        #pragma unroll
        for (int k = 0; k < 16; ++k) {
            const float4 a4 = *(const float4*)&As[k][ci];
            const float aa[4] = {a4.x, a4.y, a4.z, a4.w};
            float ww[5];
            #pragma unroll
            for (int j = 0; j < 5; ++j) ww[j] = Ws[k][cj + j];
            #pragma unroll
            for (int i = 0; i < 4; ++i)
                #pragma unroll
                for (int j = 0; j < 5; ++j)
                    acc[i][j] = fmaf(aa[i], ww[j], acc[i][j]);
        }
    }

    float* pbase = part + ((size_t)blockIdx.y * kM) * kNX;
    #pragma unroll
    for (int i = 0; i < 4; ++i)
        #pragma unroll
        for (int j = 0; j < 5; ++j)
            pbase[(size_t)(m0 + ci + i) * kNX + cj + j] = acc[i][j];
}

__global__ __launch_bounds__(256) void xproj_reduce_kernel(
    const float* __restrict__ part, float* __restrict__ xdbl)
{
    int i = blockIdx.x * 256 + threadIdx.x;    // over kM*kNX
    float s = 0.f;
    #pragma unroll
    for (int k = 0; k < kKS; ++k) s += part[(size_t)k * kM * kNX + i];
    xdbl[i] = s;
}

// ---------------------------------------------------------------------------
// causal depthwise conv (k=4) + SiLU, float4 over d
__global__ __launch_bounds__(256) void conv_silu_kernel(
    const float* __restrict__ xraw, const float* __restrict__ cw,
    const float* __restrict__ cb, float* __restrict__ xout)
{
    int i = blockIdx.x * 256 + threadIdx.x;     // over kM*kDI/4
    int d4 = i % (kDI / 4);
    int ml = i / (kDI / 4);
    int l = ml & (kL - 1);
    const int d = d4 * 4;
    float4 acc = *(const float4*)&cb[d];
    const float* base = xraw + (size_t)ml * kDI + d - 3 * (size_t)kDI;
    float4 w0 = *(const float4*)&cw[(d + 0) * 4];
    float4 w1 = *(const float4*)&cw[(d + 1) * 4];
    float4 w2 = *(const float4*)&cw[(d + 2) * 4];
    float4 w3 = *(const float4*)&cw[(d + 3) * 4];
    const float wj[4][4] = {{w0.x, w1.x, w2.x, w3.x}, {w0.y, w1.y, w2.y, w3.y},
                            {w0.z, w1.z, w2.z, w3.z}, {w0.w, w1.w, w2.w, w3.w}};
    #pragma unroll
    for (int j = 0; j < 4; ++j) {
        if (l - 3 + j >= 0) {
            float4 xv = *(const float4*)(base + (size_t)j * kDI);
            acc.x = fmaf(xv.x, wj[j][0], acc.x);
            acc.y = fmaf(xv.y, wj[j][1], acc.y);
            acc.z = fmaf(xv.z, wj[j][2], acc.z);
            acc.w = fmaf(xv.w, wj[j][3], acc.w);
        }
    }
    acc.x /= (1.f + __expf(-acc.x));
    acc.y /= (1.f + __expf(-acc.y));
    acc.z /= (1.f + __expf(-acc.z));
    acc.w /= (1.f + __expf(-acc.w));
    *(float4*)&xout[(size_t)ml * kDI + d] = acc;
}

// ---------------------------------------------------------------------------
// Selective scan v4: SEGMENTED (8 segments of 128 steps) + fused dt_proj.
// Pass 1: block = (b, d0-tile, seg); per thread (c,s): local scan with h0=0:
//   P = prod dA, Q = h_local_end, acc = sum h_loc*C*g, wc = sum cumprod*C*g,
//   ug = sum u*g.  (True contribution = acc + h0_seg * wc.)
// Pass 2: chain the 8 segments per (b,d,s), reduce over s, add D*ug.
constexpr int kNSEG = 8;
constexpr int kSEGL = kL / kNSEG;     // 128
constexpr int kT    = 64;             // steps per chunk
constexpr int kNCS  = kSEGL / kT;     // 2 chunks per segment
constexpr int kXP   = 84;             // xdS row pad
constexpr int kP    = kB * kDI * 16;  // 98304 (b,d,s) tuples

__global__ __launch_bounds__(256) void scan4_kernel(
    const float* __restrict__ x, const float* __restrict__ g,
    const float* __restrict__ xdbl, const float* __restrict__ Wd,
    const float* __restrict__ dt_bias, const float* __restrict__ A_log,
    float* __restrict__ PA, float* __restrict__ QA,
    float* __restrict__ accA, float* __restrict__ wcA,
    float* __restrict__ ugA)
{
    __shared__ float xdS[2][kT][kXP];   // full xdbl rows (dtr | B | C)
    __shared__ float uS [2][kT][16];
    __shared__ float gS [2][kT][16];
    __shared__ float dtS[2][kT][17];    // computed dt, padded
    const int t = threadIdx.x;
    const int blk = blockIdx.x;         // 0..3071
    const int seg = blk & (kNSEG - 1);
    const int bd  = blk >> 3;           // 0..383
    const int b   = bd / 96;
    const int d0  = (bd % 96) * 16;
    const int lb  = seg * kSEGL;        // segment base step

    // ---- staging maps
    const int sl = t >> 2, sc = (t & 3) << 2;              // u/g: [64][16]
    const float* x_base  = x  + ((size_t)b << 10) * kDI + d0;
    const float* g_base  = g  + ((size_t)b << 10) * kDI + d0;
    const float* xd_base = xdbl + ((size_t)b << 10) * kNX;

    // ---- scan thread identity
    const int s = t & 15;     // state
    const int c = t >> 4;     // channel in block
    const int d = d0 + c;
    const float Aval = -__expf(A_log[d * kDS + s]);

    // ---- dt-compute identity
    const int cc = t & 15, ii = t >> 4;
    float4 wreg[12];
    {
        const float* wrow = Wd + (size_t)(d0 + cc) * kDTR;
        #pragma unroll
        for (int i = 0; i < 12; ++i) wreg[i] = *(const float4*)(wrow + i * 4);
    }
    const float bn = dt_bias[d0 + cc];

    float4 r_u, r_g, r_xd[5];
    auto load_chunk = [&](int l0) {
        r_u = *(const float4*)(x_base + (size_t)(l0 + sl) * kDI + sc);
        r_g = *(const float4*)(g_base + (size_t)(l0 + sl) * kDI + sc);
        #pragma unroll
        for (int j = 0; j < 5; ++j) {
            int idx = t + 256 * j;           // 1280 float4 = [64][80]
            int row = idx / 20, col4 = idx % 20;
            r_xd[j] = *(const float4*)(xd_base + (size_t)(l0 + row) * kNX + col4 * 4);
        }
    };
    auto store_chunk = [&](int bf) {
        *(float4*)&uS[bf][sl][sc] = r_u;
        *(float4*)&gS[bf][sl][sc] = r_g;
        #pragma unroll
        for (int j = 0; j < 5; ++j) {
            int idx = t + 256 * j;
            int row = idx / 20, col4 = idx % 20;
            *(float4*)&xdS[bf][row][col4 * 4] = r_xd[j];
        }
    };
    auto compute_dt = [&](int bf) {
        #pragma unroll
        for (int q = 0; q < 4; ++q) {
            const int i = ii * 4 + q;
            float a = bn;
            #pragma unroll
            for (int k4 = 0; k4 < 12; ++k4) {
                const float4 xv = *(const float4*)&xdS[bf][i][k4 * 4];
                a = fmaf(xv.x, wreg[k4].x, a);
                a = fmaf(xv.y, wreg[k4].y, a);
                a = fmaf(xv.z, wreg[k4].z, a);
                a = fmaf(xv.w, wreg[k4].w, a);
            }
            a = (a > 20.f) ? a : log1pf(__expf(a));     // softplus
            dtS[bf][i][cc] = a;
        }
    };

    load_chunk(lb);
    store_chunk(0);
    __syncthreads();
    compute_dt(0);
    __syncthreads();

    float h = 0.f, cp = 1.f, acc = 0.f, wc = 0.f, ug = 0.f;
    for (int ck = 0; ck < kNCS; ++ck) {
        const int bu = ck & 1;
        if (ck + 1 < kNCS) load_chunk(lb + (ck + 1) * kT);
        #pragma unroll 4
        for (int i = 0; i < kT; ++i) {
            const float dtv = dtS[bu][i][c];
            const float uv  = uS [bu][i][c];
            const float gv  = gS [bu][i][c];
            const float Bv  = xdS[bu][i][kDTR + s];
            const float Cv  = xdS[bu][i][kDTR + 16 + s];
            const float dA  = __expf(dtv * Aval);
            h  = fmaf(dA, h, dtv * uv * Bv);
            cp = cp * dA;
            const float cg = Cv * gv;
            acc = fmaf(h, cg, acc);
            wc  = fmaf(cp, cg, wc);
            ug  = fmaf(uv, gv, ug);
        }
        if (ck + 1 < kNCS) {
            store_chunk(bu ^ 1);
            __syncthreads();
            compute_dt(bu ^ 1);
            __syncthreads();
        }
    }

    const int p = (((b * kDI + d) << 4) | s);
    const size_t o = (size_t)seg * kP + p;
    PA[o] = cp; QA[o] = h; accA[o] = acc; wcA[o] = wc;
    if (s == 0) ugA[(size_t)seg * (kB * kDI) + b * kDI + d] = ug;
}

// Pass 2: chain segments, reduce over states, add D*ug, write ysum.
__global__ __launch_bounds__(256) void scan_combine_kernel(
    const float* __restrict__ PA, const float* __restrict__ QA,
    const float* __restrict__ accA, const float* __restrict__ wcA,
    const float* __restrict__ ugA, const float* __restrict__ Dvec,
    float* __restrict__ ysum)
{
    const int p = blockIdx.x * 256 + threadIdx.x;   // 0..kP-1
    const int s = p & 15;
    const int bd = p >> 4;                          // b*kDI + d
    float h = 0.f, tot = 0.f;
    #pragma unroll
    for (int seg = 0; seg < kNSEG; ++seg) {
        const size_t o = (size_t)seg * kP + p;
        tot += accA[o] + h * wcA[o];
        h = fmaf(PA[o], h, QA[o]);
    }
    #pragma unroll
    for (int o2 = 1; o2 < 16; o2 <<= 1) tot += __shfl_xor(tot, o2, 64);
    if (s == 0) {
        float ug = 0.f;
        #pragma unroll
        for (int seg = 0; seg < kNSEG; ++seg)
            ug += ugA[(size_t)seg * (kB * kDI) + bd];
        ysum[bd] = tot + Dvec[bd % kDI] * ug;
    }
}

// ---------------------------------------------------------------------------
// out[b][j] = (1/L) * sum_d ysum[b][d] * Wout[j][d]
__global__ __launch_bounds__(256) void final_kernel(
    const float* __restrict__ ysum, const float* __restrict__ Wout,
    float* __restrict__ out)
{
    int gw = blockIdx.x * 4 + (threadIdx.x >> 6);
    int lane = threadIdx.x & 63;
    int b = gw / kDM;
    int j = gw - b * kDM;
    const float* yrow = ysum + (size_t)b * kDI;
    const float* wrow = Wout + (size_t)j * kDI;
    float acc = 0.f;
    for (int k = lane; k < kDI; k += 64) acc = fmaf(yrow[k], wrow[k], acc);
    #pragma unroll
    for (int o = 32; o; o >>= 1) acc += __shfl_xor(acc, o, 64);
    if (lane == 0) out[gw] = acc * (1.f / (float)kL);
}

// ---------------------------------------------------------------------------
extern "C" void kernel_launch(void* const* d_in, const int* in_sizes, int n_in,
                              void* d_out, int out_size, void* d_ws, size_t ws_size,
                              hipStream_t stream)
{
    const float* image_tokens = (const float*)d_in[0];
    const float* text_tokens  = (const float*)d_in[1];
    const float* W_txt        = (const float*)d_in[2];
    const float* b_txt        = (const float*)d_in[3];
    const float* in_proj_w    = (const float*)d_in[4];
    const float* conv_w       = (const float*)d_in[5];
    const float* conv_b       = (const float*)d_in[6];
    const float* x_proj_w     = (const float*)d_in[7];
    const float* dt_proj_w    = (const float*)d_in[8];
    const float* dt_proj_b    = (const float*)d_in[9];
    const float* A_log        = (const float*)d_in[10];
    const float* Dvec         = (const float*)d_in[11];
    const float* out_proj_w   = (const float*)d_in[12];
    float* out = (float*)d_out;

    // workspace layout (bytes, all 256B-aligned)
    char* p = (char*)d_ws;
    float* txt = (float*)p;                       p += 12288;
    unsigned short* tokb = (unsigned short*)p;    p += (size_t)kM * kDM * 2;       // 6.3 MB
    unsigned short* wb   = (unsigned short*)p;    p += (size_t)2 * kDI * kDM * 2;  // 4.7 MB
    float* xraw = (float*)p;                      p += (size_t)kM * kDI * 4;       // 25.2 MB
    float* gbuf = (float*)p;                      p += (size_t)kM * kDI * 4;       // 25.2 MB
    float* xbuf = (float*)p;                      p += (size_t)kM * kDI * 4;       // 25.2 MB
    float* xdbl = (float*)p;                      p += (size_t)kM * kNX * 4;       // 1.3 MB
    float* ysum = (float*)p;                      p += (size_t)kB * kDI * 4;
    float* part = (float*)tokb;       // 10.5 MB; tokb+wb dead after in_proj
    // segment-scan partials overlay xraw (dead after conv; dt is fused)
    float* PA   = xraw;                           // 8*kP = 786432 floats
    float* QA   = PA + (size_t)kNSEG * kP;
    float* accA = QA + (size_t)kNSEG * kP;
    float* wcA  = accA + (size_t)kNSEG * kP;
    float* ugA  = wcA + (size_t)kNSEG * kP;       // 8*kB*kDI floats

    // 1) txt projection
    txt_kernel<<<dim3(kB * kDM / 4), dim3(256), 0, stream>>>(text_tokens, W_txt, b_txt, txt);

    // 2) tokens = bf16(image + txt)
    tokens_bf16_kernel<<<dim3(kM * kDM / 4 / 256), dim3(256), 0, stream>>>(image_tokens, txt, tokb);

    // 3) cast in_proj_w to bf16
    castw_kernel<<<dim3((2 * kDI * kDM / 4 + 255) / 256), dim3(256), 0, stream>>>(
        in_proj_w, wb, 2 * kDI * kDM / 4);

    // 4) in_proj (bf16 MFMA): x half -> xraw, z half -> g = silu(z)
    mfma_inproj_kernel<<<dim3(kM / 128, 2 * kDI / 128), dim3(256), 0, stream>>>(
        tokb, wb, xraw, gbuf);

    // 5) causal conv + silu (float4)
    conv_silu_kernel<<<dim3(kM * kDI / 4 / 256), dim3(256), 0, stream>>>(
        xraw, conv_w, conv_b, xbuf);

    // 6) x_proj split-K
    xproj_splitk_kernel<<<dim3(kM / 64, kKS), dim3(256), 0, stream>>>(xbuf, x_proj_w, part);
    xproj_reduce_kernel<<<dim3(kM * kNX / 256), dim3(256), 0, stream>>>(part, xdbl);

    // 7) segmented scan pass 1 (fused dt_proj) + pass 2 combine
    scan4_kernel<<<dim3(kB * 96 * kNSEG), dim3(256), 0, stream>>>(
        xbuf, gbuf, xdbl, dt_proj_w, dt_proj_b, A_log,
        PA, QA, accA, wcA, ugA);
    scan_combine_kernel<<<dim3(kP / 256), dim3(256), 0, stream>>>(
        PA, QA, accA, wcA, ugA, Dvec, ysum);

    // 8) out = (ysum/L) @ out_proj_w.T
    final_kernel<<<dim3(kB * kDM / 4), dim3(256), 0, stream>>>(ysum, out_proj_w, out);
}

// Round 7
// 180.111 us; speedup vs baseline: 2.6816x; 1.1506x over previous
//
#include <hip/hip_runtime.h>
#include <math.h>

// Problem constants
constexpr int kB   = 4;
constexpr int kL   = 1024;
constexpr int kDM  = 768;
constexpr int kDI  = 1536;   // 2*kDM
constexpr int kDS  = 16;     // D_STATE
constexpr int kDTR = 48;     // DT_RANK
constexpr int kNX  = 80;     // DTR + 2*DS
constexpr int kM   = kB * kL; // 4096
constexpr int kLTXT = 128;

typedef __attribute__((ext_vector_type(8))) short bf16x8;
typedef __attribute__((ext_vector_type(4))) float f32x4;

__device__ inline unsigned short f2bf(float f) {
    unsigned u = __float_as_uint(f);
    u = (u + 0x7FFFu + ((u >> 16) & 1u)) >> 16;   // RNE
    return (unsigned short)u;
}

__device__ __forceinline__ void gl2lds16(const unsigned short* g, unsigned short* l) {
    __builtin_amdgcn_global_load_lds(
        (const __attribute__((address_space(1))) unsigned int*)g,
        (__attribute__((address_space(3))) unsigned int*)l, 16, 0, 0);
}

// ---------------------------------------------------------------------------
// txt[b][j] = b_txt[j] + sum_k text_tokens[b,0,k] * W_txt[j,k]
__global__ __launch_bounds__(256) void txt_kernel(
    const float* __restrict__ text, const float* __restrict__ Wt,
    const float* __restrict__ bt, float* __restrict__ txt)
{
    int gw = blockIdx.x * 4 + (threadIdx.x >> 6);
    int lane = threadIdx.x & 63;
    int b = gw / kDM;
    int j = gw - b * kDM;
    const float* trow = text + (size_t)b * kLTXT * kDM;
    const float* wrow = Wt + (size_t)j * kDM;
    float acc = 0.f;
    for (int k = lane; k < kDM; k += 64) acc = fmaf(trow[k], wrow[k], acc);
    #pragma unroll
    for (int o = 32; o; o >>= 1) acc += __shfl_xor(acc, o, 64);
    if (lane == 0) txt[gw] = acc + bt[j];
}

// ---------------------------------------------------------------------------
// tokens_bf16[m][k] = bf16(image[m][k] + txt[m/1024][k])
__global__ __launch_bounds__(256) void tokens_bf16_kernel(
    const float* __restrict__ img, const float* __restrict__ txt,
    unsigned short* __restrict__ tok)
{
    int i = blockIdx.x * 256 + threadIdx.x;        // over kM*kDM/4
    float4 a = ((const float4*)img)[i];
    int m = i / (kDM / 4);
    int k4 = i - m * (kDM / 4);
    float4 tv = ((const float4*)(txt + (size_t)(m >> 10) * kDM))[k4];
    ushort4 o;
    o.x = f2bf(a.x + tv.x); o.y = f2bf(a.y + tv.y);
    o.z = f2bf(a.z + tv.z); o.w = f2bf(a.w + tv.w);
    ((ushort4*)tok)[i] = o;
}

// ---------------------------------------------------------------------------
// cast in_proj_w (f32, [3072][768]) -> bf16
__global__ __launch_bounds__(256) void castw_kernel(
    const float* __restrict__ w, unsigned short* __restrict__ o, int n4)
{
    int i = blockIdx.x * 256 + threadIdx.x;
    if (i >= n4) return;
    float4 a = ((const float4*)w)[i];
    ushort4 v;
    v.x = f2bf(a.x); v.y = f2bf(a.y); v.z = f2bf(a.z); v.w = f2bf(a.w);
    ((ushort4*)o)[i] = v;
}

// ---------------------------------------------------------------------------
// bf16 MFMA GEMM for in_proj (global_load_lds width-16, double-buffered LDS).
// M=4096, N=3072, K=768. BM=BN=128, BK=32, 256 threads (4 waves, 2x2).
// n<1536 -> xout; n>=1536 -> gout = silu(v)
__global__ __launch_bounds__(256) void mfma_inproj_kernel(
    const unsigned short* __restrict__ A, const unsigned short* __restrict__ W,
    float* __restrict__ xout, float* __restrict__ gout)
{
    __shared__ unsigned short Asm[2][128][32];
    __shared__ unsigned short Wsm[2][128][32];
    const int t = threadIdx.x;
    const int lane = t & 63;
    const int wv = t >> 6;             // wave 0..3
    const int wr = wv >> 1, wc = wv & 1;
    const int m0 = blockIdx.x * 128;
    const int n0 = blockIdx.y * 128;

    const int srow = lane >> 2;          // 0..15
    const int scol = (lane & 3) * 8;     // bf16 elem 0,8,16,24
    const unsigned short* agp  = A + (size_t)(m0 + wv * 32 + srow) * kDM + scol;
    const unsigned short* agp2 = agp + 16 * kDM;
    const unsigned short* wgp  = W + (size_t)(n0 + wv * 32 + srow) * kDM + scol;
    const unsigned short* wgp2 = wgp + 16 * kDM;

    auto stage = [&](int buf, int k0) {
        gl2lds16(agp  + k0, &Asm[buf][wv * 32][0]);
        gl2lds16(agp2 + k0, &Asm[buf][wv * 32 + 16][0]);
        gl2lds16(wgp  + k0, &Wsm[buf][wv * 32][0]);
        gl2lds16(wgp2 + k0, &Wsm[buf][wv * 32 + 16][0]);
    };

    f32x4 acc[4][4] = {};
    const int fr = lane & 15;
    const int fk = (lane >> 4) * 8;

    stage(0, 0);
    __syncthreads();

    int buf = 0;
    for (int k0 = 0; k0 < kDM; k0 += 32) {
        if (k0 + 32 < kDM) stage(buf ^ 1, k0 + 32);
        bf16x8 af[4], wf[4];
        #pragma unroll
        for (int i = 0; i < 4; ++i)
            af[i] = *(const bf16x8*)&Asm[buf][wr * 64 + i * 16 + fr][fk];
        #pragma unroll
        for (int j = 0; j < 4; ++j)
            wf[j] = *(const bf16x8*)&Wsm[buf][wc * 64 + j * 16 + fr][fk];
        #pragma unroll
        for (int i = 0; i < 4; ++i)
            #pragma unroll
            for (int j = 0; j < 4; ++j)
                acc[i][j] = __builtin_amdgcn_mfma_f32_16x16x32_bf16(af[i], wf[j], acc[i][j], 0, 0, 0);
        __syncthreads();
        buf ^= 1;
    }

    const int erow = (lane >> 4) * 4;
    const int ecol = lane & 15;
    #pragma unroll
    for (int i = 0; i < 4; ++i) {
        #pragma unroll
        for (int j = 0; j < 4; ++j) {
            const int gn = n0 + wc * 64 + j * 16 + ecol;
            #pragma unroll
            for (int q = 0; q < 4; ++q) {
                const int gm = m0 + wr * 64 + i * 16 + erow + q;
                float v = acc[i][j][q];
                if (gn < kDI) {
                    xout[(size_t)gm * kDI + gn] = v;
                } else {
                    gout[(size_t)gm * kDI + (gn - kDI)] = v / (1.f + __expf(-v));
                }
            }
        }
    }
}

// ---------------------------------------------------------------------------
// x_proj split-K: part[ks][m][n] = sum_{k in seg ks} x[m][k] * W[n][k]
constexpr int kKS   = 8;
constexpr int kKSEG = kDI / kKS;   // 192

__global__ __launch_bounds__(256) void xproj_splitk_kernel(
    const float* __restrict__ A, const float* __restrict__ W,
    float* __restrict__ part)
{
    __shared__ float As[16][68];
    __shared__ float Ws[16][84];
    const int t = threadIdx.x;
    const int m0 = blockIdx.x * 64;
    const int kbase = blockIdx.y * kKSEG;
    const int lrow = t >> 2, lk4 = (t & 3) << 2;
    const int ci = (t & 15) << 2;      // 4 rows
    const int cj = (t >> 4) * 5;       // 5 cols (16*5 = 80)
    float acc[4][5] = {};
    const float* aptr = A + (size_t)(m0 + lrow) * kDI + kbase + lk4;

    for (int k0 = 0; k0 < kKSEG; k0 += 16) {
        float4 av = *(const float4*)(aptr + k0);
        if (k0) __syncthreads();
        As[lk4+0][lrow] = av.x; As[lk4+1][lrow] = av.y;
        As[lk4+2][lrow] = av.z; As[lk4+3][lrow] = av.w;
        #pragma unroll
        for (int i = 0; i < 5; ++i) {
            int idx = t + 256 * i;
            int n = idx % 80;
            int k = idx / 80;
            Ws[k][n] = W[(size_t)n * kDI + kbase + k0 + k];
        }
        __syncthreads();
        #pragma unroll
        for (int k = 0; k < 16; ++k) {
            const float4 a4 = *(const float4*)&As[k][ci];
            const float aa[4] = {a4.x, a4.y, a4.z, a4.w};
            float ww[5];
            #pragma unroll
            for (int j = 0; j < 5; ++j) ww[j] = Ws[k][cj + j];
            #pragma unroll
            for (int i = 0; i < 4; ++i)
                #pragma unroll
                for (int j = 0; j < 5; ++j)
                    acc[i][j] = fmaf(aa[i], ww[j], acc[i][j]);
        }
    }

    float* pbase = part + ((size_t)blockIdx.y * kM) * kNX;
    #pragma unroll
    for (int i = 0; i < 4; ++i)
        #pragma unroll
        for (int j = 0; j < 5; ++j)
            pbase[(size_t)(m0 + ci + i) * kNX + cj + j] = acc[i][j];
}

__global__ __launch_bounds__(256) void xproj_reduce_kernel(
    const float* __restrict__ part, float* __restrict__ xdbl)
{
    int i = blockIdx.x * 256 + threadIdx.x;    // over kM*kNX
    float s = 0.f;
    #pragma unroll
    for (int k = 0; k < kKS; ++k) s += part[(size_t)k * kM * kNX + i];
    xdbl[i] = s;
}

// ---------------------------------------------------------------------------
// causal depthwise conv (k=4) + SiLU, float4 over d
__global__ __launch_bounds__(256) void conv_silu_kernel(
    const float* __restrict__ xraw, const float* __restrict__ cw,
    const float* __restrict__ cb, float* __restrict__ xout)
{
    int i = blockIdx.x * 256 + threadIdx.x;     // over kM*kDI/4
    int d4 = i % (kDI / 4);
    int ml = i / (kDI / 4);
    int l = ml & (kL - 1);
    const int d = d4 * 4;
    float4 acc = *(const float4*)&cb[d];
    const float* base = xraw + (size_t)ml * kDI + d - 3 * (size_t)kDI;
    float4 w0 = *(const float4*)&cw[(d + 0) * 4];
    float4 w1 = *(const float4*)&cw[(d + 1) * 4];
    float4 w2 = *(const float4*)&cw[(d + 2) * 4];
    float4 w3 = *(const float4*)&cw[(d + 3) * 4];
    const float wj[4][4] = {{w0.x, w1.x, w2.x, w3.x}, {w0.y, w1.y, w2.y, w3.y},
                            {w0.z, w1.z, w2.z, w3.z}, {w0.w, w1.w, w2.w, w3.w}};
    #pragma unroll
    for (int j = 0; j < 4; ++j) {
        if (l - 3 + j >= 0) {
            float4 xv = *(const float4*)(base + (size_t)j * kDI);
            acc.x = fmaf(xv.x, wj[j][0], acc.x);
            acc.y = fmaf(xv.y, wj[j][1], acc.y);
            acc.z = fmaf(xv.z, wj[j][2], acc.z);
            acc.w = fmaf(xv.w, wj[j][3], acc.w);
        }
    }
    acc.x /= (1.f + __expf(-acc.x));
    acc.y /= (1.f + __expf(-acc.y));
    acc.z /= (1.f + __expf(-acc.z));
    acc.w /= (1.f + __expf(-acc.w));
    *(float4*)&xout[(size_t)ml * kDI + d] = acc;
}

// ---------------------------------------------------------------------------
// Selective scan v5: 16 segments of 64 steps, SINGLE-chunk blocks (no double
// buffer -> 34 KB LDS -> 4 blocks/CU). Fused dt_proj.
// Per thread (c,s), h0=0 local scan emits:
//   P = prod dA, Q = h_end, acc = sum h*C*g, wc = sum cumprod*C*g, ug = sum u*g
constexpr int kNSEG = 16;
constexpr int kSEGL = kL / kNSEG;     // 64
constexpr int kXP   = 84;             // xdS row pad
constexpr int kP    = kB * kDI * 16;  // 98304 (b,d,s) tuples

__global__ __launch_bounds__(256) void scan5_kernel(
    const float* __restrict__ x, const float* __restrict__ g,
    const float* __restrict__ xdbl, const float* __restrict__ Wd,
    const float* __restrict__ dt_bias, const float* __restrict__ A_log,
    float* __restrict__ PA, float* __restrict__ QA,
    float* __restrict__ accA, float* __restrict__ wcA,
    float* __restrict__ ugA)
{
    __shared__ float xdS[kSEGL][kXP];   // full xdbl rows (dtr | B | C)  21.5 KB
    __shared__ float uS [kSEGL][16];    // 4 KB
    __shared__ float gS [kSEGL][16];    // 4 KB
    __shared__ float dtS[kSEGL][17];    // 4.4 KB
    const int t = threadIdx.x;
    const int blk = blockIdx.x;         // 0..6143
    const int seg = blk & (kNSEG - 1);
    const int bd  = blk >> 4;           // 0..383
    const int b   = bd / 96;
    const int d0  = (bd % 96) * 16;
    const int lb  = seg * kSEGL;        // segment base step

    // ---- staging (single shot)
    const int sl = t >> 2, sc = (t & 3) << 2;              // u/g: [64][16]
    const float* x_base  = x  + ((size_t)b << 10) * kDI + d0;
    const float* g_base  = g  + ((size_t)b << 10) * kDI + d0;
    const float* xd_base = xdbl + ((size_t)b << 10) * kNX;

    *(float4*)&uS[sl][sc] = *(const float4*)(x_base + (size_t)(lb + sl) * kDI + sc);
    *(float4*)&gS[sl][sc] = *(const float4*)(g_base + (size_t)(lb + sl) * kDI + sc);
    #pragma unroll
    for (int j = 0; j < 5; ++j) {
        int idx = t + 256 * j;           // 1280 float4 = [64][80]
        int row = idx / 20, col4 = idx % 20;
        *(float4*)&xdS[row][col4 * 4] =
            *(const float4*)(xd_base + (size_t)(lb + row) * kNX + col4 * 4);
    }

    // ---- scan thread identity
    const int s = t & 15;     // state
    const int c = t >> 4;     // channel in block
    const int d = d0 + c;
    const float Aval = -__expf(A_log[d * kDS + s]);

    // ---- dt-compute identity
    const int cc = t & 15, ii = t >> 4;
    float4 wreg[12];
    {
        const float* wrow = Wd + (size_t)(d0 + cc) * kDTR;
        #pragma unroll
        for (int i = 0; i < 12; ++i) wreg[i] = *(const float4*)(wrow + i * 4);
    }
    const float bn = dt_bias[d0 + cc];

    __syncthreads();

    // dt = softplus(dtr @ Wd^T + b): thread (cc,ii) does rows ii*4..ii*4+3
    #pragma unroll
    for (int q = 0; q < 4; ++q) {
        const int i = ii * 4 + q;
        float a = bn;
        #pragma unroll
        for (int k4 = 0; k4 < 12; ++k4) {
            const float4 xv = *(const float4*)&xdS[i][k4 * 4];
            a = fmaf(xv.x, wreg[k4].x, a);
            a = fmaf(xv.y, wreg[k4].y, a);
            a = fmaf(xv.z, wreg[k4].z, a);
            a = fmaf(xv.w, wreg[k4].w, a);
        }
        a = (a > 20.f) ? a : log1pf(__expf(a));     // softplus
        dtS[i][cc] = a;
    }
    __syncthreads();

    float h = 0.f, cp = 1.f, acc = 0.f, wc = 0.f, ug = 0.f;
    #pragma unroll 8
    for (int i = 0; i < kSEGL; ++i) {
        const float dtv = dtS[i][c];
        const float uv  = uS [i][c];
        const float gv  = gS [i][c];
        const float Bv  = xdS[i][kDTR + s];
        const float Cv  = xdS[i][kDTR + 16 + s];
        const float dA  = __expf(dtv * Aval);
        h  = fmaf(dA, h, dtv * uv * Bv);
        cp = cp * dA;
        const float cg = Cv * gv;
        acc = fmaf(h, cg, acc);
        wc  = fmaf(cp, cg, wc);
        ug  = fmaf(uv, gv, ug);
    }

    const int p = (((b * kDI + d) << 4) | s);
    const size_t o = (size_t)seg * kP + p;
    PA[o] = cp; QA[o] = h; accA[o] = acc; wcA[o] = wc;
    if (s == 0) ugA[(size_t)seg * (kB * kDI) + b * kDI + d] = ug;
}

// Pass 2: chain segments, reduce over states, add D*ug, write ysum.
__global__ __launch_bounds__(256) void scan_combine_kernel(
    const float* __restrict__ PA, const float* __restrict__ QA,
    const float* __restrict__ accA, const float* __restrict__ wcA,
    const float* __restrict__ ugA, const float* __restrict__ Dvec,
    float* __restrict__ ysum)
{
    const int p = blockIdx.x * 256 + threadIdx.x;   // 0..kP-1
    const int s = p & 15;
    const int bd = p >> 4;                          // b*kDI + d
    float h = 0.f, tot = 0.f;
    #pragma unroll
    for (int seg = 0; seg < kNSEG; ++seg) {
        const size_t o = (size_t)seg * kP + p;
        tot += accA[o] + h * wcA[o];
        h = fmaf(PA[o], h, QA[o]);
    }
    #pragma unroll
    for (int o2 = 1; o2 < 16; o2 <<= 1) tot += __shfl_xor(tot, o2, 64);
    if (s == 0) {
        float ug = 0.f;
        #pragma unroll
        for (int seg = 0; seg < kNSEG; ++seg)
            ug += ugA[(size_t)seg * (kB * kDI) + bd];
        ysum[bd] = tot + Dvec[bd % kDI] * ug;
    }
}

// ---------------------------------------------------------------------------
// out[b][j] = (1/L) * sum_d ysum[b][d] * Wout[j][d]
__global__ __launch_bounds__(256) void final_kernel(
    const float* __restrict__ ysum, const float* __restrict__ Wout,
    float* __restrict__ out)
{
    int gw = blockIdx.x * 4 + (threadIdx.x >> 6);
    int lane = threadIdx.x & 63;
    int b = gw / kDM;
    int j = gw - b * kDM;
    const float* yrow = ysum + (size_t)b * kDI;
    const float* wrow = Wout + (size_t)j * kDI;
    float acc = 0.f;
    for (int k = lane; k < kDI; k += 64) acc = fmaf(yrow[k], wrow[k], acc);
    #pragma unroll
    for (int o = 32; o; o >>= 1) acc += __shfl_xor(acc, o, 64);
    if (lane == 0) out[gw] = acc * (1.f / (float)kL);
}

// ---------------------------------------------------------------------------
extern "C" void kernel_launch(void* const* d_in, const int* in_sizes, int n_in,
                              void* d_out, int out_size, void* d_ws, size_t ws_size,
                              hipStream_t stream)
{
    const float* image_tokens = (const float*)d_in[0];
    const float* text_tokens  = (const float*)d_in[1];
    const float* W_txt        = (const float*)d_in[2];
    const float* b_txt        = (const float*)d_in[3];
    const float* in_proj_w    = (const float*)d_in[4];
    const float* conv_w       = (const float*)d_in[5];
    const float* conv_b       = (const float*)d_in[6];
    const float* x_proj_w     = (const float*)d_in[7];
    const float* dt_proj_w    = (const float*)d_in[8];
    const float* dt_proj_b    = (const float*)d_in[9];
    const float* A_log        = (const float*)d_in[10];
    const float* Dvec         = (const float*)d_in[11];
    const float* out_proj_w   = (const float*)d_in[12];
    float* out = (float*)d_out;

    // workspace layout (bytes, all 256B-aligned)
    char* p = (char*)d_ws;
    float* txt = (float*)p;                       p += 12288;
    unsigned short* tokb = (unsigned short*)p;    p += (size_t)kM * kDM * 2;       // 6.3 MB
    unsigned short* wb   = (unsigned short*)p;    p += (size_t)2 * kDI * kDM * 2;  // 4.7 MB
    float* xraw = (float*)p;                      p += (size_t)kM * kDI * 4;       // 25.2 MB
    float* gbuf = (float*)p;                      p += (size_t)kM * kDI * 4;       // 25.2 MB
    float* xbuf = (float*)p;                      p += (size_t)kM * kDI * 4;       // 25.2 MB
    float* xdbl = (float*)p;                      p += (size_t)kM * kNX * 4;       // 1.3 MB
    float* ysum = (float*)p;                      p += (size_t)kB * kDI * 4;
    float* part = (float*)tokb;       // 10.5 MB; tokb+wb dead after in_proj
    // segment-scan partials: 4 arrays x 16*kP floats = 25.2 MB = exactly xraw
    float* PA   = xraw;               // xraw dead after conv (dt fused)
    float* QA   = PA + (size_t)kNSEG * kP;
    float* accA = QA + (size_t)kNSEG * kP;
    float* wcA  = accA + (size_t)kNSEG * kP;
    float* ugA  = part;               // 16*kB*kDI floats = 393 KB; part dead after xproj

    // 1) txt projection
    txt_kernel<<<dim3(kB * kDM / 4), dim3(256), 0, stream>>>(text_tokens, W_txt, b_txt, txt);

    // 2) tokens = bf16(image + txt)
    tokens_bf16_kernel<<<dim3(kM * kDM / 4 / 256), dim3(256), 0, stream>>>(image_tokens, txt, tokb);

    // 3) cast in_proj_w to bf16
    castw_kernel<<<dim3((2 * kDI * kDM / 4 + 255) / 256), dim3(256), 0, stream>>>(
        in_proj_w, wb, 2 * kDI * kDM / 4);

    // 4) in_proj (bf16 MFMA): x half -> xraw, z half -> g = silu(z)
    mfma_inproj_kernel<<<dim3(kM / 128, 2 * kDI / 128), dim3(256), 0, stream>>>(
        tokb, wb, xraw, gbuf);

    // 5) causal conv + silu (float4)
    conv_silu_kernel<<<dim3(kM * kDI / 4 / 256), dim3(256), 0, stream>>>(
        xraw, conv_w, conv_b, xbuf);

    // 6) x_proj split-K
    xproj_splitk_kernel<<<dim3(kM / 64, kKS), dim3(256), 0, stream>>>(xbuf, x_proj_w, part);
    xproj_reduce_kernel<<<dim3(kM * kNX / 256), dim3(256), 0, stream>>>(part, xdbl);

    // 7) segmented scan pass 1 (fused dt_proj, 16 segs, single-chunk) + combine
    scan5_kernel<<<dim3(kB * 96 * kNSEG), dim3(256), 0, stream>>>(
        xbuf, gbuf, xdbl, dt_proj_w, dt_proj_b, A_log,
        PA, QA, accA, wcA, ugA);
    scan_combine_kernel<<<dim3(kP / 256), dim3(256), 0, stream>>>(
        PA, QA, accA, wcA, ugA, Dvec, ysum);

    // 8) out = (ysum/L) @ out_proj_w.T
    final_kernel<<<dim3(kB * kDM / 4), dim3(256), 0, stream>>>(ysum, out_proj_w, out);
}

// Round 8
// 179.464 us; speedup vs baseline: 2.6912x; 1.0036x over previous
//
#include <hip/hip_runtime.h>
#include <math.h>

// Problem constants
constexpr int kB   = 4;
constexpr int kL   = 1024;
constexpr int kDM  = 768;
constexpr int kDI  = 1536;   // 2*kDM
constexpr int kDS  = 16;     // D_STATE
constexpr int kDTR = 48;     // DT_RANK
constexpr int kNX  = 80;     // DTR + 2*DS
constexpr int kM   = kB * kL; // 4096
constexpr int kLTXT = 128;

typedef __attribute__((ext_vector_type(8))) short bf16x8;
typedef __attribute__((ext_vector_type(4))) float f32x4;
typedef __attribute__((ext_vector_type(2))) float f32x2;

__device__ inline unsigned short f2bf(float f) {
    unsigned u = __float_as_uint(f);
    u = (u + 0x7FFFu + ((u >> 16) & 1u)) >> 16;   // RNE
    return (unsigned short)u;
}

__device__ __forceinline__ void gl2lds16(const unsigned short* g, unsigned short* l) {
    __builtin_amdgcn_global_load_lds(
        (const __attribute__((address_space(1))) unsigned int*)g,
        (__attribute__((address_space(3))) unsigned int*)l, 16, 0, 0);
}

// ---------------------------------------------------------------------------
// txt[b][j] = b_txt[j] + sum_k text_tokens[b,0,k] * W_txt[j,k]
__global__ __launch_bounds__(256) void txt_kernel(
    const float* __restrict__ text, const float* __restrict__ Wt,
    const float* __restrict__ bt, float* __restrict__ txt)
{
    int gw = blockIdx.x * 4 + (threadIdx.x >> 6);
    int lane = threadIdx.x & 63;
    int b = gw / kDM;
    int j = gw - b * kDM;
    const float* trow = text + (size_t)b * kLTXT * kDM;
    const float* wrow = Wt + (size_t)j * kDM;
    float acc = 0.f;
    for (int k = lane; k < kDM; k += 64) acc = fmaf(trow[k], wrow[k], acc);
    #pragma unroll
    for (int o = 32; o; o >>= 1) acc += __shfl_xor(acc, o, 64);
    if (lane == 0) txt[gw] = acc + bt[j];
}

// ---------------------------------------------------------------------------
// tokens_bf16[m][k] = bf16(image[m][k] + txt[m/1024][k])
__global__ __launch_bounds__(256) void tokens_bf16_kernel(
    const float* __restrict__ img, const float* __restrict__ txt,
    unsigned short* __restrict__ tok)
{
    int i = blockIdx.x * 256 + threadIdx.x;        // over kM*kDM/4
    float4 a = ((const float4*)img)[i];
    int m = i / (kDM / 4);
    int k4 = i - m * (kDM / 4);
    float4 tv = ((const float4*)(txt + (size_t)(m >> 10) * kDM))[k4];
    ushort4 o;
    o.x = f2bf(a.x + tv.x); o.y = f2bf(a.y + tv.y);
    o.z = f2bf(a.z + tv.z); o.w = f2bf(a.w + tv.w);
    ((ushort4*)tok)[i] = o;
}

// ---------------------------------------------------------------------------
// cast in_proj_w (f32, [3072][768]) -> bf16
__global__ __launch_bounds__(256) void castw_kernel(
    const float* __restrict__ w, unsigned short* __restrict__ o, int n4)
{
    int i = blockIdx.x * 256 + threadIdx.x;
    if (i >= n4) return;
    float4 a = ((const float4*)w)[i];
    ushort4 v;
    v.x = f2bf(a.x); v.y = f2bf(a.y); v.z = f2bf(a.z); v.w = f2bf(a.w);
    ((ushort4*)o)[i] = v;
}

// ---------------------------------------------------------------------------
// bf16 MFMA GEMM for in_proj (global_load_lds width-16, double-buffered LDS).
// M=4096, N=3072, K=768. BM=BN=128, BK=32, 256 threads (4 waves, 2x2).
// n<1536 -> xout; n>=1536 -> gout = silu(v)
__global__ __launch_bounds__(256) void mfma_inproj_kernel(
    const unsigned short* __restrict__ A, const unsigned short* __restrict__ W,
    float* __restrict__ xout, float* __restrict__ gout)
{
    __shared__ unsigned short Asm[2][128][32];
    __shared__ unsigned short Wsm[2][128][32];
    const int t = threadIdx.x;
    const int lane = t & 63;
    const int wv = t >> 6;             // wave 0..3
    const int wr = wv >> 1, wc = wv & 1;
    const int m0 = blockIdx.x * 128;
    const int n0 = blockIdx.y * 128;

    const int srow = lane >> 2;          // 0..15
    const int scol = (lane & 3) * 8;     // bf16 elem 0,8,16,24
    const unsigned short* agp  = A + (size_t)(m0 + wv * 32 + srow) * kDM + scol;
    const unsigned short* agp2 = agp + 16 * kDM;
    const unsigned short* wgp  = W + (size_t)(n0 + wv * 32 + srow) * kDM + scol;
    const unsigned short* wgp2 = wgp + 16 * kDM;

    auto stage = [&](int buf, int k0) {
        gl2lds16(agp  + k0, &Asm[buf][wv * 32][0]);
        gl2lds16(agp2 + k0, &Asm[buf][wv * 32 + 16][0]);
        gl2lds16(wgp  + k0, &Wsm[buf][wv * 32][0]);
        gl2lds16(wgp2 + k0, &Wsm[buf][wv * 32 + 16][0]);
    };

    f32x4 acc[4][4] = {};
    const int fr = lane & 15;
    const int fk = (lane >> 4) * 8;

    stage(0, 0);
    __syncthreads();

    int buf = 0;
    for (int k0 = 0; k0 < kDM; k0 += 32) {
        if (k0 + 32 < kDM) stage(buf ^ 1, k0 + 32);
        bf16x8 af[4], wf[4];
        #pragma unroll
        for (int i = 0; i < 4; ++i)
            af[i] = *(const bf16x8*)&Asm[buf][wr * 64 + i * 16 + fr][fk];
        #pragma unroll
        for (int j = 0; j < 4; ++j)
            wf[j] = *(const bf16x8*)&Wsm[buf][wc * 64 + j * 16 + fr][fk];
        #pragma unroll
        for (int i = 0; i < 4; ++i)
            #pragma unroll
            for (int j = 0; j < 4; ++j)
                acc[i][j] = __builtin_amdgcn_mfma_f32_16x16x32_bf16(af[i], wf[j], acc[i][j], 0, 0, 0);
        __syncthreads();
        buf ^= 1;
    }

    const int erow = (lane >> 4) * 4;
    const int ecol = lane & 15;
    #pragma unroll
    for (int i = 0; i < 4; ++i) {
        #pragma unroll
        for (int j = 0; j < 4; ++j) {
            const int gn = n0 + wc * 64 + j * 16 + ecol;
            #pragma unroll
            for (int q = 0; q < 4; ++q) {
                const int gm = m0 + wr * 64 + i * 16 + erow + q;
                float v = acc[i][j][q];
                if (gn < kDI) {
                    xout[(size_t)gm * kDI + gn] = v;
                } else {
                    gout[(size_t)gm * kDI + (gn - kDI)] = v / (1.f + __expf(-v));
                }
            }
        }
    }
}

// ---------------------------------------------------------------------------
// x_proj split-K: part[ks][m][n] = sum_{k in seg ks} x[m][k] * W[n][k]
constexpr int kKS   = 8;
constexpr int kKSEG = kDI / kKS;   // 192

__global__ __launch_bounds__(256) void xproj_splitk_kernel(
    const float* __restrict__ A, const float* __restrict__ W,
    float* __restrict__ part)
{
    __shared__ float As[16][68];
    __shared__ float Ws[16][84];
    const int t = threadIdx.x;
    const int m0 = blockIdx.x * 64;
    const int kbase = blockIdx.y * kKSEG;
    const int lrow = t >> 2, lk4 = (t & 3) << 2;
    const int ci = (t & 15) << 2;      // 4 rows
    const int cj = (t >> 4) * 5;       // 5 cols (16*5 = 80)
    float acc[4][5] = {};
    const float* aptr = A + (size_t)(m0 + lrow) * kDI + kbase + lk4;

    for (int k0 = 0; k0 < kKSEG; k0 += 16) {
        float4 av = *(const float4*)(aptr + k0);
        if (k0) __syncthreads();
        As[lk4+0][lrow] = av.x; As[lk4+1][lrow] = av.y;
        As[lk4+2][lrow] = av.z; As[lk4+3][lrow] = av.w;
        #pragma unroll
        for (int i = 0; i < 5; ++i) {
            int idx = t + 256 * i;
            int n = idx % 80;
            int k = idx / 80;
            Ws[k][n] = W[(size_t)n * kDI + kbase + k0 + k];
        }
        __syncthreads();
        #pragma unroll
        for (int k = 0; k < 16; ++k) {
            const float4 a4 = *(const float4*)&As[k][ci];
            const float aa[4] = {a4.x, a4.y, a4.z, a4.w};
            float ww[5];
            #pragma unroll
            for (int j = 0; j < 5; ++j) ww[j] = Ws[k][cj + j];
            #pragma unroll
            for (int i = 0; i < 4; ++i)
                #pragma unroll
                for (int j = 0; j < 5; ++j)
                    acc[i][j] = fmaf(aa[i], ww[j], acc[i][j]);
        }
    }

    float* pbase = part + ((size_t)blockIdx.y * kM) * kNX;
    #pragma unroll
    for (int i = 0; i < 4; ++i)
        #pragma unroll
        for (int j = 0; j < 5; ++j)
            pbase[(size_t)(m0 + ci + i) * kNX + cj + j] = acc[i][j];
}

__global__ __launch_bounds__(256) void xproj_reduce_kernel(
    const float* __restrict__ part, float* __restrict__ xdbl)
{
    int i = blockIdx.x * 256 + threadIdx.x;    // over kM*kNX
    float s = 0.f;
    #pragma unroll
    for (int k = 0; k < kKS; ++k) s += part[(size_t)k * kM * kNX + i];
    xdbl[i] = s;
}

// ---------------------------------------------------------------------------
// causal depthwise conv (k=4) + SiLU, float4 over d
__global__ __launch_bounds__(256) void conv_silu_kernel(
    const float* __restrict__ xraw, const float* __restrict__ cw,
    const float* __restrict__ cb, float* __restrict__ xout)
{
    int i = blockIdx.x * 256 + threadIdx.x;     // over kM*kDI/4
    int d4 = i % (kDI / 4);
    int ml = i / (kDI / 4);
    int l = ml & (kL - 1);
    const int d = d4 * 4;
    float4 acc = *(const float4*)&cb[d];
    const float* base = xraw + (size_t)ml * kDI + d - 3 * (size_t)kDI;
    float4 w0 = *(const float4*)&cw[(d + 0) * 4];
    float4 w1 = *(const float4*)&cw[(d + 1) * 4];
    float4 w2 = *(const float4*)&cw[(d + 2) * 4];
    float4 w3 = *(const float4*)&cw[(d + 3) * 4];
    const float wj[4][4] = {{w0.x, w1.x, w2.x, w3.x}, {w0.y, w1.y, w2.y, w3.y},
                            {w0.z, w1.z, w2.z, w3.z}, {w0.w, w1.w, w2.w, w3.w}};
    #pragma unroll
    for (int j = 0; j < 4; ++j) {
        if (l - 3 + j >= 0) {
            float4 xv = *(const float4*)(base + (size_t)j * kDI);
            acc.x = fmaf(xv.x, wj[j][0], acc.x);
            acc.y = fmaf(xv.y, wj[j][1], acc.y);
            acc.z = fmaf(xv.z, wj[j][2], acc.z);
            acc.w = fmaf(xv.w, wj[j][3], acc.w);
        }
    }
    acc.x /= (1.f + __expf(-acc.x));
    acc.y /= (1.f + __expf(-acc.y));
    acc.z /= (1.f + __expf(-acc.z));
    acc.w /= (1.f + __expf(-acc.w));
    *(float4*)&xout[(size_t)ml * kDI + d] = acc;
}

// ---------------------------------------------------------------------------
// Selective scan v6: 16 segments x 64 steps; block = 32 channels x 8 threads,
// each thread owns the contiguous STATE PAIR (2sp, 2sp+1) -> float2/pk math,
// B/C as ds_read_b64, per-channel dt/u/g loaded once per pair.
// dt (fused dt_proj) overwrites the dead dtr columns of xdS (cols 0..31).
constexpr int kNSEG = 16;
constexpr int kSEGL = kL / kNSEG;     // 64
constexpr int kCH   = 32;             // channels per block
constexpr int kXP   = 84;             // xdS row pad
constexpr int kP    = kB * kDI * 16;  // 98304 (b,d,s) tuples
constexpr float kLOG2E = 1.44269504089f;

__global__ __launch_bounds__(256, 4) void scan6_kernel(
    const float* __restrict__ x, const float* __restrict__ g,
    const float* __restrict__ xdbl, const float* __restrict__ Wd,
    const float* __restrict__ dt_bias, const float* __restrict__ A_log,
    float* __restrict__ PA, float* __restrict__ QA,
    float* __restrict__ accA, float* __restrict__ wcA,
    float* __restrict__ ugA)
{
    __shared__ float xdS[kSEGL][kXP];   // dtr (->dt overlay) | B | C   21.5 KB
    __shared__ float uS [kSEGL][kCH];   // 8 KB
    __shared__ float gS [kSEGL][kCH];   // 8 KB
    const int t = threadIdx.x;
    const int blk = blockIdx.x;         // 0..3071
    const int seg = blk & (kNSEG - 1);
    const int bd  = blk >> 4;           // 0..191
    const int b   = bd / 48;
    const int d0  = (bd % 48) * kCH;
    const int lb  = seg * kSEGL;        // segment base step

    // ---- staging (single shot)
    const float* x_base  = x  + ((size_t)b << 10) * kDI + d0;
    const float* g_base  = g  + ((size_t)b << 10) * kDI + d0;
    const float* xd_base = xdbl + ((size_t)b << 10) * kNX;

    #pragma unroll
    for (int j = 0; j < 2; ++j) {       // u/g: 512 float4 each
        int idx = t + 256 * j;
        int row = idx >> 3, c4 = (idx & 7) * 4;
        *(float4*)&uS[row][c4] = *(const float4*)(x_base + (size_t)(lb + row) * kDI + c4);
        *(float4*)&gS[row][c4] = *(const float4*)(g_base + (size_t)(lb + row) * kDI + c4);
    }
    #pragma unroll
    for (int j = 0; j < 5; ++j) {       // xd: 1280 float4 = [64][80]
        int idx = t + 256 * j;
        int row = idx / 20, c4 = idx % 20;
        *(float4*)&xdS[row][c4 * 4] =
            *(const float4*)(xd_base + (size_t)(lb + row) * kNX + c4 * 4);
    }

    // ---- thread identity
    const int c  = t & 31;     // channel in block
    const int sp = t >> 5;     // state-pair index (states 2sp, 2sp+1)
    const int d  = d0 + c;
    f32x2 Av2;
    Av2.x = -__expf(A_log[d * kDS + 2 * sp])     * kLOG2E;
    Av2.y = -__expf(A_log[d * kDS + 2 * sp + 1]) * kLOG2E;

    // ---- dt weights (row for this channel; redundant across sp, L2-hot)
    float4 wreg[12];
    {
        const float* wrow = Wd + (size_t)d * kDTR;
        #pragma unroll
        for (int i = 0; i < 12; ++i) wreg[i] = *(const float4*)(wrow + i * 4);
    }
    const float bn = dt_bias[d];

    __syncthreads();

    // ---- dt = softplus(dtr @ Wd^T + b): thread (c, sp) does rows sp*8..sp*8+7
    float dtv[8];
    #pragma unroll
    for (int q = 0; q < 8; ++q) {
        const int r = sp * 8 + q;
        float a = bn;
        #pragma unroll
        for (int k4 = 0; k4 < 12; ++k4) {
            const float4 xv = *(const float4*)&xdS[r][k4 * 4];
            a = fmaf(xv.x, wreg[k4].x, a);
            a = fmaf(xv.y, wreg[k4].y, a);
            a = fmaf(xv.z, wreg[k4].z, a);
            a = fmaf(xv.w, wreg[k4].w, a);
        }
        dtv[q] = (a > 20.f) ? a : log1pf(__expf(a));   // softplus
    }
    __syncthreads();
    #pragma unroll
    for (int q = 0; q < 8; ++q) xdS[sp * 8 + q][c] = dtv[q];   // overlay dtr
    __syncthreads();

    // ---- scan (2 states per thread, packed)
    f32x2 h = {0.f, 0.f}, cp = {1.f, 1.f}, acc = {0.f, 0.f}, wc = {0.f, 0.f};
    float ug = 0.f;
    #pragma unroll 8
    for (int i = 0; i < kSEGL; ++i) {
        const float dtc = xdS[i][c];
        const float uv  = uS [i][c];
        const float gv  = gS [i][c];
        const f32x2 Bv = *(const f32x2*)&xdS[i][kDTR + 2 * sp];
        const f32x2 Cv = *(const f32x2*)&xdS[i][kDTR + 16 + 2 * sp];
        const f32x2 pm = dtc * Av2;                    // packed mul
        f32x2 dA;
        dA.x = exp2f(pm.x);
        dA.y = exp2f(pm.y);
        const float dtu = dtc * uv;
        h  = dA * h + dtu * Bv;                        // packed fma
        cp = cp * dA;
        const f32x2 cg = Cv * gv;
        acc = h * cg + acc;
        wc  = cp * cg + wc;
        ug  = fmaf(uv, gv, ug);
    }

    const int p = ((b * kDI + d) << 4) + 2 * sp;       // even -> float2 aligned
    const size_t o = (size_t)seg * kP + p;
    *(f32x2*)&PA[o]   = cp;
    *(f32x2*)&QA[o]   = h;
    *(f32x2*)&accA[o] = acc;
    *(f32x2*)&wcA[o]  = wc;
    if (sp == 0) ugA[(size_t)seg * (kB * kDI) + b * kDI + d] = ug;
}

// Pass 2: chain segments, reduce over states, add D*ug, write ysum.
__global__ __launch_bounds__(256) void scan_combine_kernel(
    const float* __restrict__ PA, const float* __restrict__ QA,
    const float* __restrict__ accA, const float* __restrict__ wcA,
    const float* __restrict__ ugA, const float* __restrict__ Dvec,
    float* __restrict__ ysum)
{
    const int p = blockIdx.x * 256 + threadIdx.x;   // 0..kP-1
    const int s = p & 15;
    const int bd = p >> 4;                          // b*kDI + d
    float h = 0.f, tot = 0.f;
    #pragma unroll
    for (int seg = 0; seg < kNSEG; ++seg) {
        const size_t o = (size_t)seg * kP + p;
        tot += accA[o] + h * wcA[o];
        h = fmaf(PA[o], h, QA[o]);
    }
    #pragma unroll
    for (int o2 = 1; o2 < 16; o2 <<= 1) tot += __shfl_xor(tot, o2, 64);
    if (s == 0) {
        float ug = 0.f;
        #pragma unroll
        for (int seg = 0; seg < kNSEG; ++seg)
            ug += ugA[(size_t)seg * (kB * kDI) + bd];
        ysum[bd] = tot + Dvec[bd % kDI] * ug;
    }
}

// ---------------------------------------------------------------------------
// out[b][j] = (1/L) * sum_d ysum[b][d] * Wout[j][d]
__global__ __launch_bounds__(256) void final_kernel(
    const float* __restrict__ ysum, const float* __restrict__ Wout,
    float* __restrict__ out)
{
    int gw = blockIdx.x * 4 + (threadIdx.x >> 6);
    int lane = threadIdx.x & 63;
    int b = gw / kDM;
    int j = gw - b * kDM;
    const float* yrow = ysum + (size_t)b * kDI;
    const float* wrow = Wout + (size_t)j * kDI;
    float acc = 0.f;
    for (int k = lane; k < kDI; k += 64) acc = fmaf(yrow[k], wrow[k], acc);
    #pragma unroll
    for (int o = 32; o; o >>= 1) acc += __shfl_xor(acc, o, 64);
    if (lane == 0) out[gw] = acc * (1.f / (float)kL);
}

// ---------------------------------------------------------------------------
extern "C" void kernel_launch(void* const* d_in, const int* in_sizes, int n_in,
                              void* d_out, int out_size, void* d_ws, size_t ws_size,
                              hipStream_t stream)
{
    const float* image_tokens = (const float*)d_in[0];
    const float* text_tokens  = (const float*)d_in[1];
    const float* W_txt        = (const float*)d_in[2];
    const float* b_txt        = (const float*)d_in[3];
    const float* in_proj_w    = (const float*)d_in[4];
    const float* conv_w       = (const float*)d_in[5];
    const float* conv_b       = (const float*)d_in[6];
    const float* x_proj_w     = (const float*)d_in[7];
    const float* dt_proj_w    = (const float*)d_in[8];
    const float* dt_proj_b    = (const float*)d_in[9];
    const float* A_log        = (const float*)d_in[10];
    const float* Dvec         = (const float*)d_in[11];
    const float* out_proj_w   = (const float*)d_in[12];
    float* out = (float*)d_out;

    // workspace layout (bytes, all 256B-aligned)
    char* p = (char*)d_ws;
    float* txt = (float*)p;                       p += 12288;
    unsigned short* tokb = (unsigned short*)p;    p += (size_t)kM * kDM * 2;       // 6.3 MB
    unsigned short* wb   = (unsigned short*)p;    p += (size_t)2 * kDI * kDM * 2;  // 4.7 MB
    float* xraw = (float*)p;                      p += (size_t)kM * kDI * 4;       // 25.2 MB
    float* gbuf = (float*)p;                      p += (size_t)kM * kDI * 4;       // 25.2 MB
    float* xbuf = (float*)p;                      p += (size_t)kM * kDI * 4;       // 25.2 MB
    float* xdbl = (float*)p;                      p += (size_t)kM * kNX * 4;       // 1.3 MB
    float* ysum = (float*)p;                      p += (size_t)kB * kDI * 4;
    float* part = (float*)tokb;       // 10.5 MB; tokb+wb dead after in_proj
    // segment-scan partials: 4 arrays x 16*kP floats = 25.2 MB = exactly xraw
    float* PA   = xraw;               // xraw dead after conv (dt fused)
    float* QA   = PA + (size_t)kNSEG * kP;
    float* accA = QA + (size_t)kNSEG * kP;
    float* wcA  = accA + (size_t)kNSEG * kP;
    float* ugA  = part;               // 16*kB*kDI floats = 393 KB; part dead after xproj

    // 1) txt projection
    txt_kernel<<<dim3(kB * kDM / 4), dim3(256), 0, stream>>>(text_tokens, W_txt, b_txt, txt);

    // 2) tokens = bf16(image + txt)
    tokens_bf16_kernel<<<dim3(kM * kDM / 4 / 256), dim3(256), 0, stream>>>(image_tokens, txt, tokb);

    // 3) cast in_proj_w to bf16
    castw_kernel<<<dim3((2 * kDI * kDM / 4 + 255) / 256), dim3(256), 0, stream>>>(
        in_proj_w, wb, 2 * kDI * kDM / 4);

    // 4) in_proj (bf16 MFMA): x half -> xraw, z half -> g = silu(z)
    mfma_inproj_kernel<<<dim3(kM / 128, 2 * kDI / 128), dim3(256), 0, stream>>>(
        tokb, wb, xraw, gbuf);

    // 5) causal conv + silu (float4)
    conv_silu_kernel<<<dim3(kM * kDI / 4 / 256), dim3(256), 0, stream>>>(
        xraw, conv_w, conv_b, xbuf);

    // 6) x_proj split-K
    xproj_splitk_kernel<<<dim3(kM / 64, kKS), dim3(256), 0, stream>>>(xbuf, x_proj_w, part);
    xproj_reduce_kernel<<<dim3(kM * kNX / 256), dim3(256), 0, stream>>>(part, xdbl);

    // 7) segmented scan pass 1 (32ch blocks, state-pair packed) + combine
    scan6_kernel<<<dim3(kB * 48 * kNSEG), dim3(256), 0, stream>>>(
        xbuf, gbuf, xdbl, dt_proj_w, dt_proj_b, A_log,
        PA, QA, accA, wcA, ugA);
    scan_combine_kernel<<<dim3(kP / 256), dim3(256), 0, stream>>>(
        PA, QA, accA, wcA, ugA, Dvec, ysum);

    // 8) out = (ysum/L) @ out_proj_w.T
    final_kernel<<<dim3(kB * kDM / 4), dim3(256), 0, stream>>>(ysum, out_proj_w, out);
}